// Round 6
// baseline (359.796 us; speedup 1.0000x reference)
//
#include <hip/hip_runtime.h>
#include <stdint.h>

// ---------------------------------------------------------------------------
// Q_Attention: quantized ViT attention block, bit-faithful to the JAX/numpy ref.
// B=32, N=512, C=768, H=12, hd=64.  All GEMMs on i8 MFMA (int32 acc, exact).
// R17: gemm_qkv K-loop ported to the m97 staged structure (the measured-
// proven MI355X GEMM shape): global_load_lds (width 16) stages the contiguous
// fragment-major A (16KB) and B (4KB) kt-chunks into double-buffered LDS;
// fragments come from ds_read_b128 at the SAME relative offsets as the old
// direct global loads (same bytes -> same lanes -> bit-identical); 1 barrier
// per kt.  B is staged once per block (was loaded 4x, once per wave).
// R14/R15/R16 all plateaued at 68-70us / MfmaUtil 17% on per-wave direct
// global fragment loads -- this is the structural fix the learn_hip ladder
// measured at 2x the MFMA utilization.  attn / gemm_proj unchanged from R16.
// ---------------------------------------------------------------------------

#define BB 32
#define NN 512
#define CC 768
#define HH 12
#define HD 64
#define M_ROWS (BB * NN)     // 16384
#define QKV_C (3 * CC)       // 2304
#define KTA ((size_t)M_ROWS * 64)   // x0q kt-slice stride
#define KTB ((size_t)QKV_C * 64)    // wq  kt-slice stride
#define KTP ((size_t)CC * 64)       // pwq kt-slice stride

typedef int v4i __attribute__((ext_vector_type(4)));
typedef int v16i __attribute__((ext_vector_type(16)));

__device__ __forceinline__ float fadd(float a, float b) { return __fadd_rn(a, b); }
__device__ __forceinline__ float fmul(float a, float b) { return __fmul_rn(a, b); }
__device__ __forceinline__ float fdiv(float a, float b) { return __fdiv_rn(a, b); }
__device__ __forceinline__ float fsub(float a, float b) { return __fsub_rn(a, b); }

// async global->LDS 16B copy (dest = wave-uniform base + lane*16)
__device__ __forceinline__ void gload_lds16(const int8_t* g, int8_t* l) {
  __builtin_amdgcn_global_load_lds(
      (const __attribute__((address_space(1))) void*)g,
      (__attribute__((address_space(3))) void*)l, 16, 0, 0);
}

// numpy pairwise_sum, n=96 (no remainder): 8 accumulators, then pairwise combine
__device__ float np_sum_96(const float* a) {
  float r[8];
#pragma unroll
  for (int j = 0; j < 8; j++) r[j] = a[j];
  for (int i = 8; i < 96; i += 8)
#pragma unroll
    for (int j = 0; j < 8; j++) r[j] = fadd(r[j], a[i + j]);
  return fadd(fadd(fadd(r[0], r[1]), fadd(r[2], r[3])),
              fadd(fadd(r[4], r[5]), fadd(r[6], r[7])));
}

// numpy pairwise mean of 12: 8-acc combine + 4 sequential remainder adds
__device__ float np_mean_12(const float* a) {
  float r[8];
#pragma unroll
  for (int j = 0; j < 8; j++) r[j] = a[j];
  float res = fadd(fadd(fadd(r[0], r[1]), fadd(r[2], r[3])),
                   fadd(fadd(r[4], r[5]), fadd(r[6], r[7])));
  res = fadd(res, a[8]);
  res = fadd(res, a[9]);
  res = fadd(res, a[10]);
  res = fadd(res, a[11]);
  return fdiv(res, 12.0f);
}

// ---------------------------------------------------------------------------
// prep: scalar means + folded LN quant params + integer qkv bias
// scal: [0]=a_in [1]=qact_m [2]=kact_m [3]=vact_m [4]=attnact_m [5]=pact_m
// qparams: [0:64]=qalpha [64:128]=qbias [128:192]=kalpha [192:256]=kbias
// ---------------------------------------------------------------------------
__global__ void prep_kernel(const float* __restrict__ qkv_act_alpha,
                            const float* __restrict__ proj_act_alpha,
                            const float* __restrict__ qact_alpha,
                            const float* __restrict__ kact_alpha,
                            const float* __restrict__ vact_alpha,
                            const float* __restrict__ attnact_alpha,
                            const float* __restrict__ normq_w,
                            const float* __restrict__ normq_b,
                            const float* __restrict__ normk_w,
                            const float* __restrict__ normk_b,
                            const float* __restrict__ qkv_bias,
                            const float* __restrict__ qkv_alpha,
                            float* __restrict__ scal,
                            float* __restrict__ qparams,
                            float* __restrict__ biasq) {
  __shared__ float s_scal[8];
  __shared__ float chunk[16];
  int tid = threadIdx.x;
  if (tid < 8) chunk[tid] = np_sum_96(qkv_act_alpha + 96 * tid);
  else if (tid < 16) chunk[tid] = np_sum_96(proj_act_alpha + 96 * (tid - 8));
  if (tid == 16) s_scal[1] = np_mean_12(qact_alpha);
  if (tid == 17) s_scal[2] = np_mean_12(kact_alpha);
  if (tid == 18) s_scal[3] = np_mean_12(vact_alpha);
  if (tid == 19) s_scal[4] = np_mean_12(attnact_alpha);
  __syncthreads();
  if (tid == 0) {
    float s0 = fadd(fadd(chunk[0], chunk[1]), fadd(chunk[2], chunk[3]));
    float s1 = fadd(fadd(chunk[4], chunk[5]), fadd(chunk[6], chunk[7]));
    s_scal[0] = fdiv(fadd(s0, s1), 768.0f);
    float p0 = fadd(fadd(chunk[8], chunk[9]), fadd(chunk[10], chunk[11]));
    float p1 = fadd(fadd(chunk[12], chunk[13]), fadd(chunk[14], chunk[15]));
    s_scal[5] = fdiv(fadd(p0, p1), 768.0f);
  }
  __syncthreads();
  if (tid < 6) scal[tid] = s_scal[tid];
  if (tid < 64) {
    qparams[tid]       = fdiv(s_scal[1], normq_w[tid]);    // act_a / nw
    qparams[64 + tid]  = fdiv(normq_b[tid], normq_w[tid]); // nb / nw
    qparams[128 + tid] = fdiv(s_scal[2], normk_w[tid]);
    qparams[192 + tid] = fdiv(normk_b[tid], normk_w[tid]);
  }
  float a_in = s_scal[0];
  for (int c = tid; c < QKV_C; c += blockDim.x)
    biasq[c] = truncf(fdiv(fdiv(qkv_bias[c], a_in), qkv_alpha[c]));
}

// fragment-major address within a kt-slice: 32-row groups of 2KB;
// byte (row, b) -> (row&~31)*64 + (b>>4)*512 + (row&31)*16 + (b&15)
__device__ __forceinline__ size_t fragaddr(int row, int b) {
  return (size_t)(row & ~31) * 64 + ((b >> 4) * 512 + (row & 31) * 16 + (b & 15));
}

// x0_q = round(clip(x0 / a_in, -8, 7)) -> int8, fragment-major [12][...]
__global__ void quant_x0_kernel(const float* __restrict__ x0,
                                const float* __restrict__ scal,
                                int8_t* __restrict__ x0q, int total4) {
  int i = blockIdx.x * blockDim.x + threadIdx.x;
  if (i >= total4) return;
  float a_in = scal[0];
  float4 v = ((const float4*)x0)[i];
  char4 o;
  o.x = (int8_t)rintf(fminf(fmaxf(fdiv(v.x, a_in), -8.f), 7.f));
  o.y = (int8_t)rintf(fminf(fmaxf(fdiv(v.y, a_in), -8.f), 7.f));
  o.z = (int8_t)rintf(fminf(fmaxf(fdiv(v.z, a_in), -8.f), 7.f));
  o.w = (int8_t)rintf(fminf(fmaxf(fdiv(v.w, a_in), -8.f), 7.f));
  int seq = i / 192;
  int kp = (i - seq * 192) * 4;  // global channel, multiple of 4
  int b = kp & 63;
  *(char4*)(x0q + (size_t)(kp >> 6) * KTA + fragaddr(seq, b)) = o;
}

// row-wise 4-bit weight quant -> fragment-major [K/64][...]
__global__ void quant_w_kernel(const float* __restrict__ w,
                               const float* __restrict__ alpha,
                               int8_t* __restrict__ wq, int rows, int total) {
  int i = blockIdx.x * blockDim.x + threadIdx.x;
  if (i >= total) return;
  int row = i / CC;
  int k = i - row * CC;
  float t = fminf(fmaxf(fdiv(w[i], alpha[row]), -8.f), 7.f);
  wq[(size_t)(k >> 6) * ((size_t)rows * 64) + fragaddr(row, k)] =
      (int8_t)rintf(t);
}

// ---------------------------------------------------------------------------
// GEMM1 (i8 MFMA 32x32x32), R17 m97-staged: block = 256seq x 64ch, 4 waves
// each 64x64 (acc = 4 v16i = 64 AGPRs).  Per kt: global_load_lds stages the
// contiguous 16KB A-chunk (4 x 16B/thread) + 4KB B-chunk (1 x 16B/thread)
// into double-buffered LDS; fragments via ds_read_b128 at the same relative
// offsets as the old direct global loads (bit-identical operands); 8 MFMAs;
// one barrier.  B staged once per block (was 4x).  Epilogues unchanged.
// ---------------------------------------------------------------------------
__global__ __launch_bounds__(256) void gemm_qkv_kernel(
    const int8_t* __restrict__ Aq, const int8_t* __restrict__ Wq,
    const float* __restrict__ biasq, const float* __restrict__ scal,
    const float* __restrict__ qkv_alpha, const float* __restrict__ qparams,
    int8_t* __restrict__ q2, int8_t* __restrict__ k2,
    int8_t* __restrict__ v2f) {
  __shared__ __align__(16) int8_t sA[2][16384];    // 256 rows x 64 k, frag-major
  __shared__ __align__(16) int8_t sB[2][4096];     // 64 cols x 64 k, frag-major
  __shared__ __align__(16) int8_t packT[4][3072];  // per-wave pack tile

  const int L = blockIdx.x;
  const int xcd = L & 7, s = L >> 3;
  const int rb = xcd + 8 * (s / 36);   // A 256-row slice 0..63 (XCD-resident)
  const int g = s % 36;                // column head 0..35
  const int tid = threadIdx.x;
  const int w = tid >> 6, lane = tid & 63;
  const int l31 = lane & 31, hi = lane >> 5;
  const int sec = g / HH, head = g % HH;
  const int col0 = g * 64;
  const int b_idx = rb >> 1, nbase = (rb & 1) * 256;
  const int w64 = w * 64;
  const size_t bh = (size_t)b_idx * HH + head;

  v16i acc00 = (v16i)(0), acc01 = (v16i)(0);
  v16i acc10 = (v16i)(0), acc11 = (v16i)(0);

  const int8_t* Ag = Aq + (size_t)(rb * 256) * 64;  // + kt*KTA: 16KB contiguous
  const int8_t* Bg = Wq + (size_t)col0 * 64;        // + kt*KTB: 4KB contiguous
  const int t16 = tid * 16;
  const int foff = hi * 512 + l31 * 16;  // fragment lane offset
  const bool qk = (sec < 2);

  // prologue: stage kt=0 into buf 0
  {
    const int8_t* ga = Ag + t16;
#pragma unroll
    for (int i = 0; i < 4; i++)
      gload_lds16(ga + i * 4096, &sA[0][i * 4096 + t16]);
    gload_lds16(Bg + t16, &sB[0][t16]);
  }
  __syncthreads();

#pragma unroll 1
  for (int kt = 0; kt < 12; kt++) {
    const int cur = kt & 1;
    if (kt < 11) {
      const int8_t* ga = Ag + (size_t)(kt + 1) * KTA + t16;
#pragma unroll
      for (int i = 0; i < 4; i++)
        gload_lds16(ga + i * 4096, &sA[cur ^ 1][i * 4096 + t16]);
      gload_lds16(Bg + (size_t)(kt + 1) * KTB + t16, &sB[cur ^ 1][t16]);
    }
    v4i A0a = *(const v4i*)&sA[cur][w * 4096 + foff];
    v4i A0b = *(const v4i*)&sA[cur][w * 4096 + foff + 1024];
    v4i A1a = *(const v4i*)&sA[cur][w * 4096 + foff + 2048];
    v4i A1b = *(const v4i*)&sA[cur][w * 4096 + foff + 3072];
    v4i B0a = *(const v4i*)&sB[cur][foff];
    v4i B0b = *(const v4i*)&sB[cur][foff + 1024];
    v4i B1a = *(const v4i*)&sB[cur][foff + 2048];
    v4i B1b = *(const v4i*)&sB[cur][foff + 3072];
    if (qk) {  // D = W * X^T
      acc00 = __builtin_amdgcn_mfma_i32_32x32x32_i8(B0a, A0a, acc00, 0, 0, 0);
      acc01 = __builtin_amdgcn_mfma_i32_32x32x32_i8(B1a, A0a, acc01, 0, 0, 0);
      acc10 = __builtin_amdgcn_mfma_i32_32x32x32_i8(B0a, A1a, acc10, 0, 0, 0);
      acc11 = __builtin_amdgcn_mfma_i32_32x32x32_i8(B1a, A1a, acc11, 0, 0, 0);
      acc00 = __builtin_amdgcn_mfma_i32_32x32x32_i8(B0b, A0b, acc00, 0, 0, 0);
      acc01 = __builtin_amdgcn_mfma_i32_32x32x32_i8(B1b, A0b, acc01, 0, 0, 0);
      acc10 = __builtin_amdgcn_mfma_i32_32x32x32_i8(B0b, A1b, acc10, 0, 0, 0);
      acc11 = __builtin_amdgcn_mfma_i32_32x32x32_i8(B1b, A1b, acc11, 0, 0, 0);
    } else {   // D = X * W^T
      acc00 = __builtin_amdgcn_mfma_i32_32x32x32_i8(A0a, B0a, acc00, 0, 0, 0);
      acc01 = __builtin_amdgcn_mfma_i32_32x32x32_i8(A0a, B1a, acc01, 0, 0, 0);
      acc10 = __builtin_amdgcn_mfma_i32_32x32x32_i8(A1a, B0a, acc10, 0, 0, 0);
      acc11 = __builtin_amdgcn_mfma_i32_32x32x32_i8(A1a, B1a, acc11, 0, 0, 0);
      acc00 = __builtin_amdgcn_mfma_i32_32x32x32_i8(A0b, B0b, acc00, 0, 0, 0);
      acc01 = __builtin_amdgcn_mfma_i32_32x32x32_i8(A0b, B1b, acc01, 0, 0, 0);
      acc10 = __builtin_amdgcn_mfma_i32_32x32x32_i8(A1b, B0b, acc10, 0, 0, 0);
      acc11 = __builtin_amdgcn_mfma_i32_32x32x32_i8(A1b, B1b, acc11, 0, 0, 0);
    }
    __syncthreads();
  }

  if (qk) {  // q/k: LN epilogue x2 passes (lane: seq=l31, ch=32i+8b+4hi+c)
    const float* ap = qparams + (sec == 0 ? 0 : 128);
    int8_t* dst = (sec == 0) ? q2 : k2;
#pragma unroll
    for (int p = 0; p < 2; p++) {
      float xs[2][16];
#pragma unroll
      for (int i = 0; i < 2; i++)
#pragma unroll
        for (int b = 0; b < 4; b++) {
          int cg = col0 + 32 * i + 8 * b + 4 * hi;
          float4 bqv = *(const float4*)(biasq + cg);
          float4 alv = *(const float4*)(qkv_alpha + cg);
          const float* bqp = (const float*)&bqv;
          const float* alp = (const float*)&alv;
#pragma unroll
          for (int c = 0; c < 4; c++) {
            int av;
            if (p == 0)
              av = (i == 0) ? acc00[4 * b + c] : acc01[4 * b + c];
            else
              av = (i == 0) ? acc10[4 * b + c] : acc11[4 * b + c];
            xs[i][4 * b + c] = fmul(fadd((float)av, bqp[c]), alp[c]);
          }
        }
      // numpy-order stats: acc idx = ch&7 = 4hi+c (lane-local), t = ch>>3
      float rc[4];
#pragma unroll
      for (int c = 0; c < 4; c++) rc[c] = xs[0][c];
#pragma unroll
      for (int b = 1; b < 4; b++)
#pragma unroll
        for (int c = 0; c < 4; c++) rc[c] = fadd(rc[c], xs[0][4 * b + c]);
#pragma unroll
      for (int b = 0; b < 4; b++)
#pragma unroll
        for (int c = 0; c < 4; c++) rc[c] = fadd(rc[c], xs[1][4 * b + c]);
      float Ls = fadd(fadd(rc[0], rc[1]), fadd(rc[2], rc[3]));
      float Rs = __shfl_xor(Ls, 32, 64);
      float mn = fdiv(fadd(Ls, Rs), 64.0f);  // fadd commutative: lanes agree
      float vc[4];
#pragma unroll
      for (int c = 0; c < 4; c++) {
        float d = fsub(xs[0][c], mn);
        vc[c] = fmul(d, d);
      }
#pragma unroll
      for (int b = 1; b < 4; b++)
#pragma unroll
        for (int c = 0; c < 4; c++) {
          float d = fsub(xs[0][4 * b + c], mn);
          vc[c] = fadd(vc[c], fmul(d, d));
        }
#pragma unroll
      for (int b = 0; b < 4; b++)
#pragma unroll
        for (int c = 0; c < 4; c++) {
          float d = fsub(xs[1][4 * b + c], mn);
          vc[c] = fadd(vc[c], fmul(d, d));
        }
      float Lv = fadd(fadd(vc[0], vc[1]), fadd(vc[2], vc[3]));
      float Rv = __shfl_xor(Lv, 32, 64);
      float var = fdiv(fadd(Lv, Rv), 63.0f);
      float den = fadd(__fsqrt_rn(var), 1e-5f);
#pragma unroll
      for (int i = 0; i < 2; i++)
#pragma unroll
        for (int b = 0; b < 4; b++) {
          int cin = 32 * i + 8 * b + 4 * hi;  // channel-in-head
          float4 a4 = *(const float4*)(ap + cin);
          float4 b4 = *(const float4*)(ap + 64 + cin);
          const float* a4p = (const float*)&a4;
          const float* b4p = (const float*)&b4;
          uint32_t pk = 0;
#pragma unroll
          for (int c = 0; c < 4; c++) {
            float xn = fdiv(fsub(xs[i][4 * b + c], mn), den);
            float t = fdiv(fadd(xn, b4p[c]), a4p[c]);
            t = fminf(fmaxf(t, -4.f), 3.f);
            pk |= ((uint32_t)(uint8_t)(int8_t)rintf(t)) << (8 * c);
          }
          *(uint32_t*)&packT[w][l31 * 80 + cin] = pk;
        }
      asm volatile("s_waitcnt lgkmcnt(0)" ::: "memory");
      size_t rowbase = bh * NN + nbase + w64 + p * 32;
#pragma unroll
      for (int c = 0; c < 2; c++) {
        int id = lane + 64 * c;
        int row = id >> 2, off = (id & 3) * 16;  // 32 rows x 64 B
        int4 ov = *(const int4*)&packT[w][row * 80 + off];
        *(int4*)(dst + (rowbase + row) * 64 + off) = ov;
      }
    }
  } else {  // v epilogue (lane: ch = 32sj + l31, seq = 8b+4hi+c in group)
    const float a_in = scal[0], vact = scal[3];
#pragma unroll
    for (int p = 0; p < 2; p++) {
#pragma unroll
      for (int sj = 0; sj < 2; sj++) {
        int cg = col0 + 32 * sj + l31;
        float bq = biasq[cg];
        float va = fdiv(vact, fmul(a_in, qkv_alpha[cg]));
        int dloc = 32 * sj + l31;
#pragma unroll
        for (int b = 0; b < 4; b++) {
          uint32_t pk = 0;
#pragma unroll
          for (int c = 0; c < 4; c++) {
            int av;
            if (p == 0)
              av = (sj == 0) ? acc00[4 * b + c] : acc01[4 * b + c];
            else
              av = (sj == 0) ? acc10[4 * b + c] : acc11[4 * b + c];
            float vint = fadd((float)av, bq);
            float t = fminf(fmaxf(fdiv(vint, va), -4.f), 3.f);
            pk |= ((uint32_t)(uint8_t)(int8_t)rintf(t)) << (8 * c);
          }
          *(uint32_t*)&packT[w][dloc * 48 + 8 * b + 4 * hi] = pk;
        }
      }
      asm volatile("s_waitcnt lgkmcnt(0)" ::: "memory");
      // fragment-major V store: chunk (d=row, n0..n0+15) -> v2f addr
#pragma unroll
      for (int c = 0; c < 2; c++) {
        int id = lane + 64 * c;
        int row = id >> 1, off = (id & 1) * 16;  // 64 d-rows x 32 B
        int4 ov = *(const int4*)&packT[w][row * 48 + off];
        int n0 = nbase + w64 + p * 32 + off;
        *(int4*)(v2f + (size_t)bh * 32768 + ((n0 >> 6) * 4096) +
                 ((row >> 4) * 1024) + ((row & 15) * 64) +
                 (((n0 >> 4) & 3) * 16)) = ov;
      }
    }
  }
}

// ---------------------------------------------------------------------------
// Attention (i8 MFMA), per (qtile64, b*h).  XCD-affine decode: the 8 qt-blocks
// of one (b,h) head run consecutively on one XCD -> K/V head L2-resident.
// Barrier-free K-loops (R13): fragments loaded directly from global (coalesced
// 1KB wave-loads).  R16 register diet: mpack[4..7] lives in LDS (per-wave
// contiguous 1KB slabs -> conflict-free b128), kfr rotation 2-slot.
// Unchanged from R16.
// ---------------------------------------------------------------------------
__global__ __launch_bounds__(256) void attn_kernel(
    const int8_t* __restrict__ q2, const int8_t* __restrict__ k2,
    const int8_t* __restrict__ v2f, const float* __restrict__ scal,
    int8_t* __restrict__ x1q) {
  __shared__ __align__(16) int8_t At[64][80];
  __shared__ __align__(16) uint32_t mpL[4096];  // mpack kt=4..7: 16KB

  const int L = blockIdx.x;
  const int xcd = L & 7, s = L >> 3;
  const int bh = xcd + 8 * (s >> 3);   // head 0..383 (XCD-resident K/V)
  const int qt = s & 7;                // q tile 0..7
  const int tid = threadIdx.x;
  const int w = tid >> 6, lane = tid & 63, quad = lane >> 4, c16 = lane & 15;
  const int sr = tid >> 2, scol = (tid & 3) << 4;
  const float attnm = scal[4];
  const float coef =
      fmul(1.4426950408889634f, fmul(fmul(0.125f, scal[1]), scal[2]));
  const float coef128 = fmul(coef, 128.f);
  const size_t base = (size_t)bh * NN * HD;  // 32768 per head (q2/k2/v2f)
  const int mpbase = w * 1024 + lane * 4;    // per-thread mpL slot base

  // per-lane fragment base pointers (lane offset = c16*64 + quad*16)
  const int8_t* kptr = k2 + base + (size_t)c16 * 64 + quad * 16;
  const int8_t* vptr = v2f + base + (size_t)c16 * 64 + quad * 16;
  v4i qf = *(const v4i*)(q2 + base + (size_t)(qt * 64 + 16 * w + c16) * 64 +
                         quad * 16);

  // ---- pass A: QK^T, m -> regs (kt<4) / LDS (kt>=4), row sums of 2^m ----
  // kf position p = kt*4+f at kptr + p*1024 ; 2-slot rotation
  uint32_t mpack[4][4];
  float Srow = 0.f;
  v4i kfr[2];
  kfr[0] = *(const v4i*)(kptr);
  kfr[1] = *(const v4i*)(kptr + 1024);
#pragma unroll
  for (int kt = 0; kt < 8; kt++) {
    float psum = 0.f;
    uint32_t mp[4];
#pragma unroll
    for (int f = 0; f < 4; f++) {
      int p = kt * 4 + f;
      v4i kf = kfr[p & 1];
      if (p + 2 < 32) kfr[p & 1] = *(const v4i*)(kptr + (p + 2) * 1024);
      v4i d2 = (v4i){0, 0, 0, 0};
      d2 = __builtin_amdgcn_mfma_i32_16x16x64_i8(kf, qf, d2, 0, 0, 0);
      uint32_t pk = 0;
#pragma unroll
      for (int r = 0; r < 4; r++) {
        float e = truncf(fmul(coef128, (float)d2[r]));
        int mi = (int)rintf(fmul(e, 0.0078125f));
        psum = fadd(psum, ldexpf(1.0f, mi));
        pk |= ((uint32_t)(uint8_t)(int8_t)mi) << (8 * r);
      }
      mp[f] = pk;
    }
    if (kt < 4) {
#pragma unroll
      for (int f = 0; f < 4; f++) mpack[kt][f] = mp[f];
    } else {
      int4 st;
      st.x = (int)mp[0]; st.y = (int)mp[1]; st.z = (int)mp[2]; st.w = (int)mp[3];
      *(int4*)&mpL[mpbase + (kt - 4) * 256] = st;
    }
    psum = fadd(psum, __shfl_xor(psum, 16, 64));
    psum = fadd(psum, __shfl_xor(psum, 32, 64));
    Srow = fadd(Srow, psum);
  }
  const float u = fdiv(fdiv(1.0f, Srow), attnm);

  // ---- pass B: requantize from register/LDS m, AV ----
  // vf(kt,s2) = vptr + kt*4096 + s2*1024 ; 4-slot rotation
  v4i xacc[4];
#pragma unroll
  for (int s2 = 0; s2 < 4; s2++) xacc[s2] = (v4i){0, 0, 0, 0};
  v4i vfr[4];
#pragma unroll
  for (int s2 = 0; s2 < 4; s2++)
    vfr[s2] = *(const v4i*)(vptr + s2 * 1024);

#pragma unroll
  for (int kt = 0; kt < 8; kt++) {
    uint32_t mp[4];
    if (kt < 4) {
#pragma unroll
      for (int f = 0; f < 4; f++) mp[f] = mpack[kt][f];
    } else {
      int4 ld = *(const int4*)&mpL[mpbase + (kt - 4) * 256];
      mp[0] = (uint32_t)ld.x; mp[1] = (uint32_t)ld.y;
      mp[2] = (uint32_t)ld.z; mp[3] = (uint32_t)ld.w;
    }
#pragma unroll
    for (int f = 0; f < 4; f++) {
      uint32_t pk = mp[f];
      uint32_t wpk = 0;
#pragma unroll
      for (int r = 0; r < 4; r++) {
        int mi = (int)(int8_t)(pk >> (8 * r));
        float t = fminf(ldexpf(u, mi), 7.f);
        wpk |= ((uint32_t)(uint8_t)(int8_t)rintf(t)) << (8 * r);
      }
      *(uint32_t*)&At[16 * w + c16][16 * f + 4 * quad] = wpk;
    }
    asm volatile("s_waitcnt lgkmcnt(0)" ::: "memory");
    v4i af = *(const v4i*)&At[16 * w + c16][quad * 16];
#pragma unroll
    for (int s2 = 0; s2 < 4; s2++) {
      v4i vf = vfr[s2];
      if (kt < 7)
        vfr[s2] = *(const v4i*)(vptr + (kt + 1) * 4096 + s2 * 1024);
      xacc[s2] = __builtin_amdgcn_mfma_i32_16x16x64_i8(vf, af, xacc[s2], 0, 0, 0);
    }
  }

  // ---- output requant + transpose (reuse At; single barrier) ----
  const float pa = fdiv(scal[5], fmul(attnm, scal[3]));
#pragma unroll
  for (int s2 = 0; s2 < 4; s2++) {
    uint32_t pack = 0;
#pragma unroll
    for (int r = 0; r < 4; r++) {
      float t = fminf(fmaxf(fdiv((float)xacc[s2][r], pa), -4.f), 3.f);
      pack |= ((uint32_t)(uint8_t)(int8_t)rintf(t)) << (8 * r);
    }
    *(uint32_t*)&At[16 * w + c16][16 * s2 + 4 * quad] = pack;
  }
  __syncthreads();
  int4 ov = *(const int4*)&At[sr][scol];
  *(int4*)(x1q + ((size_t)bh * NN + qt * 64 + sr) * HD + scol) = ov;
}

// ---------------------------------------------------------------------------
// GEMM2 (i8 MFMA 32x32x32): barrier-free, LDS-free.  Block = 256seq x 64ch,
// wave = 64x64 (acc = 4 v16i = 64 AGPRs, 4 chains).  B (pwq) loaded
// just-in-time (L2-hot, 12 sharer blocks); A (x1q) 1-deep register dbuf.
// Epilogue in two 32-row passes.  Unchanged from R16.
// ---------------------------------------------------------------------------
__global__ __launch_bounds__(256) void gemm_proj_kernel(
    const int8_t* __restrict__ x1q, const int8_t* __restrict__ Wq,
    const float* __restrict__ proj_alpha, const float* __restrict__ proj_bias,
    const float* __restrict__ scal, float* __restrict__ out) {
  const int L = blockIdx.x;
  const int xcd = L & 7, s = L >> 3;
  const int rb = xcd + 8 * (s / 12);   // 256-row slice 0..63 (XCD-resident)
  const int g = s % 12;                // column block 0..11
  const int tid = threadIdx.x;
  const int w = tid >> 6, lane = tid & 63;
  const int l31 = lane & 31, hi = lane >> 5;
  const int col0 = g * 64;
  const int b_idx = rb >> 1, nbase = (rb & 1) * 256;
  const int w64 = w * 64;

  v16i acc00 = (v16i)(0), acc01 = (v16i)(0);
  v16i acc10 = (v16i)(0), acc11 = (v16i)(0);

  const int8_t* pa =
      x1q + ((size_t)b_idx * HH * NN + nbase + w64 + l31) * 64 + hi * 16;
  const int8_t* pb = Wq + (size_t)col0 * 64 + hi * 512 + l31 * 16;
  const size_t KTX = (size_t)NN * 64;  // head stride in x1q

  v4i A0a = *(const v4i*)(pa);
  v4i A0b = *(const v4i*)(pa + 32);
  v4i A1a = *(const v4i*)(pa + 2048);
  v4i A1b = *(const v4i*)(pa + 2048 + 32);
#pragma unroll 1
  for (int kt = 0; kt < 11; kt++) {
    const int8_t* pbk = pb + (size_t)kt * KTP;
    v4i B0a = *(const v4i*)(pbk);
    v4i B0b = *(const v4i*)(pbk + 1024);
    v4i B1a = *(const v4i*)(pbk + 2048);
    v4i B1b = *(const v4i*)(pbk + 3072);
    const int8_t* npa = pa + (size_t)(kt + 1) * KTX;
    v4i nA0a = *(const v4i*)(npa);
    v4i nA0b = *(const v4i*)(npa + 32);
    v4i nA1a = *(const v4i*)(npa + 2048);
    v4i nA1b = *(const v4i*)(npa + 2048 + 32);
    acc00 = __builtin_amdgcn_mfma_i32_32x32x32_i8(B0a, A0a, acc00, 0, 0, 0);
    acc01 = __builtin_amdgcn_mfma_i32_32x32x32_i8(B1a, A0a, acc01, 0, 0, 0);
    acc10 = __builtin_amdgcn_mfma_i32_32x32x32_i8(B0a, A1a, acc10, 0, 0, 0);
    acc11 = __builtin_amdgcn_mfma_i32_32x32x32_i8(B1a, A1a, acc11, 0, 0, 0);
    acc00 = __builtin_amdgcn_mfma_i32_32x32x32_i8(B0b, A0b, acc00, 0, 0, 0);
    acc01 = __builtin_amdgcn_mfma_i32_32x32x32_i8(B1b, A0b, acc01, 0, 0, 0);
    acc10 = __builtin_amdgcn_mfma_i32_32x32x32_i8(B0b, A1b, acc10, 0, 0, 0);
    acc11 = __builtin_amdgcn_mfma_i32_32x32x32_i8(B1b, A1b, acc11, 0, 0, 0);
    A0a = nA0a; A0b = nA0b; A1a = nA1a; A1b = nA1b;
  }
  {  // kt = 11 tail
    const int8_t* pbk = pb + (size_t)11 * KTP;
    v4i B0a = *(const v4i*)(pbk);
    v4i B0b = *(const v4i*)(pbk + 1024);
    v4i B1a = *(const v4i*)(pbk + 2048);
    v4i B1b = *(const v4i*)(pbk + 3072);
    acc00 = __builtin_amdgcn_mfma_i32_32x32x32_i8(B0a, A0a, acc00, 0, 0, 0);
    acc01 = __builtin_amdgcn_mfma_i32_32x32x32_i8(B1a, A0a, acc01, 0, 0, 0);
    acc10 = __builtin_amdgcn_mfma_i32_32x32x32_i8(B0a, A1a, acc10, 0, 0, 0);
    acc11 = __builtin_amdgcn_mfma_i32_32x32x32_i8(B1a, A1a, acc11, 0, 0, 0);
    acc00 = __builtin_amdgcn_mfma_i32_32x32x32_i8(B0b, A0b, acc00, 0, 0, 0);
    acc01 = __builtin_amdgcn_mfma_i32_32x32x32_i8(B1b, A0b, acc01, 0, 0, 0);
    acc10 = __builtin_amdgcn_mfma_i32_32x32x32_i8(B0b, A1b, acc10, 0, 0, 0);
    acc11 = __builtin_amdgcn_mfma_i32_32x32x32_i8(B1b, A1b, acc11, 0, 0, 0);
  }

  const float pact = scal[5];
#pragma unroll
  for (int p = 0; p < 2; p++) {
    const int m = rb * 256 + w64 + p * 32 + l31;
#pragma unroll
    for (int i = 0; i < 2; i++)
#pragma unroll
      for (int b = 0; b < 4; b++) {
        int colb = col0 + 32 * i + 8 * b + 4 * hi;
        float4 al = *(const float4*)(proj_alpha + colb);
        float4 bi = *(const float4*)(proj_bias + colb);
        const float* alp = (const float*)&al;
        const float* bip = (const float*)&bi;
        float4 o;
        float* op = (float*)&o;
#pragma unroll
        for (int c = 0; c < 4; c++) {
          int av;
          if (p == 0)
            av = (i == 0) ? acc00[4 * b + c] : acc01[4 * b + c];
          else
            av = (i == 0) ? acc10[4 * b + c] : acc11[4 * b + c];
          op[c] = fadd(fmul(fmul((float)av, alp[c]), pact), bip[c]);
        }
        *(float4*)(out + (size_t)m * CC + colb) = o;
      }
  }
}

extern "C" void kernel_launch(void* const* d_in, const int* in_sizes, int n_in,
                              void* d_out, int out_size, void* d_ws,
                              size_t ws_size, hipStream_t stream) {
  const float* x0 = (const float*)d_in[0];
  const float* qkv_w = (const float*)d_in[1];
  const float* qkv_alpha = (const float*)d_in[2];
  const float* qkv_bias = (const float*)d_in[3];
  const float* qkv_act_alpha = (const float*)d_in[4];
  const float* proj_w = (const float*)d_in[5];
  const float* proj_alpha = (const float*)d_in[6];
  const float* proj_bias = (const float*)d_in[7];
  const float* proj_act_alpha = (const float*)d_in[8];
  const float* normq_w = (const float*)d_in[9];
  const float* normq_b = (const float*)d_in[10];
  const float* normk_w = (const float*)d_in[11];
  const float* normk_b = (const float*)d_in[12];
  const float* qact_alpha = (const float*)d_in[13];
  const float* kact_alpha = (const float*)d_in[14];
  const float* vact_alpha = (const float*)d_in[15];
  const float* attnact_alpha = (const float*)d_in[16];

  char* ws = (char*)d_ws;
  size_t off = 0;
  auto alloc = [&](size_t bytes) -> char* {
    char* p = ws + off;
    off += (bytes + 255) & ~(size_t)255;
    return p;
  };
  float* scal = (float*)alloc(64 * 4);
  float* qparams = (float*)alloc(256 * 4);
  float* biasq = (float*)alloc(QKV_C * 4);
  int8_t* x0q = (int8_t*)alloc((size_t)M_ROWS * CC);   // frag-major [12][...]
  int8_t* wq = (int8_t*)alloc((size_t)QKV_C * CC);     // frag-major [12][...]
  int8_t* pwq = (int8_t*)alloc((size_t)CC * CC);       // frag-major [12][...]
  int8_t* q2 = (int8_t*)alloc((size_t)BB * HH * NN * HD);
  int8_t* k2 = (int8_t*)alloc((size_t)BB * HH * NN * HD);
  int8_t* v2f = (int8_t*)alloc((size_t)BB * HH * NN * HD);  // fragment-major
  int8_t* x1q = (int8_t*)alloc((size_t)M_ROWS * CC);

  prep_kernel<<<1, 256, 0, stream>>>(qkv_act_alpha, proj_act_alpha, qact_alpha,
                                     kact_alpha, vact_alpha, attnact_alpha,
                                     normq_w, normq_b, normk_w, normk_b,
                                     qkv_bias, qkv_alpha, scal, qparams, biasq);

  int total4 = M_ROWS * CC / 4;
  quant_x0_kernel<<<(total4 + 255) / 256, 256, 0, stream>>>(x0, scal, x0q,
                                                            total4);
  quant_w_kernel<<<(QKV_C * CC + 255) / 256, 256, 0, stream>>>(
      qkv_w, qkv_alpha, wq, QKV_C, QKV_C * CC);
  quant_w_kernel<<<(CC * CC + 255) / 256, 256, 0, stream>>>(
      proj_w, proj_alpha, pwq, CC, CC * CC);

  gemm_qkv_kernel<<<36 * (M_ROWS / 256), 256, 0, stream>>>(
      x0q, wq, biasq, scal, qkv_alpha, qparams, q2, k2, v2f);

  attn_kernel<<<(NN / 64) * (BB * HH), 256, 0, stream>>>(q2, k2, v2f, scal,
                                                         x1q);

  gemm_proj_kernel<<<12 * (M_ROWS / 256), 256, 0, stream>>>(
      x1q, pwq, proj_alpha, proj_bias, scal, (float*)d_out);
}

// Round 7
// 292.472 us; speedup vs baseline: 1.2302x; 1.2302x over previous
//
#include <hip/hip_runtime.h>
#include <stdint.h>

// ---------------------------------------------------------------------------
// Q_Attention: quantized ViT attention block, bit-faithful to the JAX/numpy ref.
// B=32, N=512, C=768, H=12, hd=64.  All GEMMs on i8 MFMA (int32 acc, exact).
// R18: R17's LDS-staged gemm_qkv REVERTED (200 regs + 53KB LDS -> 11% occ,
// vmcnt(0) drain per kt -> 168us).  Back to R16 shape, but with the K-loops
// FULLY UNROLLED and all explicit prefetch/rotation removed: guide m131-m141
// measured that hand-pipelining (unroll-1 + rotate movs) pins the schedule
// and forces a hard wait per iteration; a fully-visible unrolled loop lets
// LLVM's pressure-aware scheduler hoist loads to its own depth with counted
// waitcnts.  Same loads, same MFMA order per accumulator -> bit-identical.
// attn / prep / quant unchanged from R16 (single-variable experiment).
// ---------------------------------------------------------------------------

#define BB 32
#define NN 512
#define CC 768
#define HH 12
#define HD 64
#define M_ROWS (BB * NN)     // 16384
#define QKV_C (3 * CC)       // 2304
#define KTA ((size_t)M_ROWS * 64)   // x0q kt-slice stride
#define KTB ((size_t)QKV_C * 64)    // wq  kt-slice stride
#define KTP ((size_t)CC * 64)       // pwq kt-slice stride

typedef int v4i __attribute__((ext_vector_type(4)));
typedef int v16i __attribute__((ext_vector_type(16)));

__device__ __forceinline__ float fadd(float a, float b) { return __fadd_rn(a, b); }
__device__ __forceinline__ float fmul(float a, float b) { return __fmul_rn(a, b); }
__device__ __forceinline__ float fdiv(float a, float b) { return __fdiv_rn(a, b); }
__device__ __forceinline__ float fsub(float a, float b) { return __fsub_rn(a, b); }

// numpy pairwise_sum, n=96 (no remainder): 8 accumulators, then pairwise combine
__device__ float np_sum_96(const float* a) {
  float r[8];
#pragma unroll
  for (int j = 0; j < 8; j++) r[j] = a[j];
  for (int i = 8; i < 96; i += 8)
#pragma unroll
    for (int j = 0; j < 8; j++) r[j] = fadd(r[j], a[i + j]);
  return fadd(fadd(fadd(r[0], r[1]), fadd(r[2], r[3])),
              fadd(fadd(r[4], r[5]), fadd(r[6], r[7])));
}

// numpy pairwise mean of 12: 8-acc combine + 4 sequential remainder adds
__device__ float np_mean_12(const float* a) {
  float r[8];
#pragma unroll
  for (int j = 0; j < 8; j++) r[j] = a[j];
  float res = fadd(fadd(fadd(r[0], r[1]), fadd(r[2], r[3])),
                   fadd(fadd(r[4], r[5]), fadd(r[6], r[7])));
  res = fadd(res, a[8]);
  res = fadd(res, a[9]);
  res = fadd(res, a[10]);
  res = fadd(res, a[11]);
  return fdiv(res, 12.0f);
}

// ---------------------------------------------------------------------------
// prep: scalar means + folded LN quant params + integer qkv bias
// scal: [0]=a_in [1]=qact_m [2]=kact_m [3]=vact_m [4]=attnact_m [5]=pact_m
// qparams: [0:64]=qalpha [64:128]=qbias [128:192]=kalpha [192:256]=kbias
// ---------------------------------------------------------------------------
__global__ void prep_kernel(const float* __restrict__ qkv_act_alpha,
                            const float* __restrict__ proj_act_alpha,
                            const float* __restrict__ qact_alpha,
                            const float* __restrict__ kact_alpha,
                            const float* __restrict__ vact_alpha,
                            const float* __restrict__ attnact_alpha,
                            const float* __restrict__ normq_w,
                            const float* __restrict__ normq_b,
                            const float* __restrict__ normk_w,
                            const float* __restrict__ normk_b,
                            const float* __restrict__ qkv_bias,
                            const float* __restrict__ qkv_alpha,
                            float* __restrict__ scal,
                            float* __restrict__ qparams,
                            float* __restrict__ biasq) {
  __shared__ float s_scal[8];
  __shared__ float chunk[16];
  int tid = threadIdx.x;
  if (tid < 8) chunk[tid] = np_sum_96(qkv_act_alpha + 96 * tid);
  else if (tid < 16) chunk[tid] = np_sum_96(proj_act_alpha + 96 * (tid - 8));
  if (tid == 16) s_scal[1] = np_mean_12(qact_alpha);
  if (tid == 17) s_scal[2] = np_mean_12(kact_alpha);
  if (tid == 18) s_scal[3] = np_mean_12(vact_alpha);
  if (tid == 19) s_scal[4] = np_mean_12(attnact_alpha);
  __syncthreads();
  if (tid == 0) {
    float s0 = fadd(fadd(chunk[0], chunk[1]), fadd(chunk[2], chunk[3]));
    float s1 = fadd(fadd(chunk[4], chunk[5]), fadd(chunk[6], chunk[7]));
    s_scal[0] = fdiv(fadd(s0, s1), 768.0f);
    float p0 = fadd(fadd(chunk[8], chunk[9]), fadd(chunk[10], chunk[11]));
    float p1 = fadd(fadd(chunk[12], chunk[13]), fadd(chunk[14], chunk[15]));
    s_scal[5] = fdiv(fadd(p0, p1), 768.0f);
  }
  __syncthreads();
  if (tid < 6) scal[tid] = s_scal[tid];
  if (tid < 64) {
    qparams[tid]       = fdiv(s_scal[1], normq_w[tid]);    // act_a / nw
    qparams[64 + tid]  = fdiv(normq_b[tid], normq_w[tid]); // nb / nw
    qparams[128 + tid] = fdiv(s_scal[2], normk_w[tid]);
    qparams[192 + tid] = fdiv(normk_b[tid], normk_w[tid]);
  }
  float a_in = s_scal[0];
  for (int c = tid; c < QKV_C; c += blockDim.x)
    biasq[c] = truncf(fdiv(fdiv(qkv_bias[c], a_in), qkv_alpha[c]));
}

// fragment-major address within a kt-slice: 32-row groups of 2KB;
// byte (row, b) -> (row&~31)*64 + (b>>4)*512 + (row&31)*16 + (b&15)
__device__ __forceinline__ size_t fragaddr(int row, int b) {
  return (size_t)(row & ~31) * 64 + ((b >> 4) * 512 + (row & 31) * 16 + (b & 15));
}

// x0_q = round(clip(x0 / a_in, -8, 7)) -> int8, fragment-major [12][...]
__global__ void quant_x0_kernel(const float* __restrict__ x0,
                                const float* __restrict__ scal,
                                int8_t* __restrict__ x0q, int total4) {
  int i = blockIdx.x * blockDim.x + threadIdx.x;
  if (i >= total4) return;
  float a_in = scal[0];
  float4 v = ((const float4*)x0)[i];
  char4 o;
  o.x = (int8_t)rintf(fminf(fmaxf(fdiv(v.x, a_in), -8.f), 7.f));
  o.y = (int8_t)rintf(fminf(fmaxf(fdiv(v.y, a_in), -8.f), 7.f));
  o.z = (int8_t)rintf(fminf(fmaxf(fdiv(v.z, a_in), -8.f), 7.f));
  o.w = (int8_t)rintf(fminf(fmaxf(fdiv(v.w, a_in), -8.f), 7.f));
  int seq = i / 192;
  int kp = (i - seq * 192) * 4;  // global channel, multiple of 4
  int b = kp & 63;
  *(char4*)(x0q + (size_t)(kp >> 6) * KTA + fragaddr(seq, b)) = o;
}

// row-wise 4-bit weight quant -> fragment-major [K/64][...]
__global__ void quant_w_kernel(const float* __restrict__ w,
                               const float* __restrict__ alpha,
                               int8_t* __restrict__ wq, int rows, int total) {
  int i = blockIdx.x * blockDim.x + threadIdx.x;
  if (i >= total) return;
  int row = i / CC;
  int k = i - row * CC;
  float t = fminf(fmaxf(fdiv(w[i], alpha[row]), -8.f), 7.f);
  wq[(size_t)(k >> 6) * ((size_t)rows * 64) + fragaddr(row, k)] =
      (int8_t)rintf(t);
}

// ---------------------------------------------------------------------------
// GEMM1 (i8 MFMA 32x32x32): barrier-free.  Block = 256seq x 64ch; 4 waves
// each own 64seq x 64ch (acc = 4 v16i = 64 AGPRs, 4 independent MFMA chains).
// R18: K-loop fully unrolled, no explicit prefetch/rotation -- LLVM's
// pressure-aware scheduler picks the pipeline depth and counted waitcnts.
// Fragment-major layout: every operand load = one coalesced 1024B request.
// Epilogues: two 32-row passes through packT (LDS in-order per wave).
// ---------------------------------------------------------------------------
__global__ __launch_bounds__(256) void gemm_qkv_kernel(
    const int8_t* __restrict__ Aq, const int8_t* __restrict__ Wq,
    const float* __restrict__ biasq, const float* __restrict__ scal,
    const float* __restrict__ qkv_alpha, const float* __restrict__ qparams,
    int8_t* __restrict__ q2, int8_t* __restrict__ k2,
    int8_t* __restrict__ v2f) {
  __shared__ __align__(16) int8_t packT[4][3072];  // per-wave pack tile

  const int L = blockIdx.x;
  const int xcd = L & 7, s = L >> 3;
  const int rb = xcd + 8 * (s / 36);   // A 256-row slice 0..63 (XCD-resident)
  const int g = s % 36;                // column head 0..35
  const int tid = threadIdx.x;
  const int w = tid >> 6, lane = tid & 63;
  const int l31 = lane & 31, hi = lane >> 5;
  const int sec = g / HH, head = g % HH;
  const int col0 = g * 64;
  const int b_idx = rb >> 1, nbase = (rb & 1) * 256;
  const int w64 = w * 64;
  const size_t bh = (size_t)b_idx * HH + head;

  v16i acc00 = (v16i)(0), acc01 = (v16i)(0);
  v16i acc10 = (v16i)(0), acc11 = (v16i)(0);

  // fragment-major pointers: lane offset = hi*512 + l31*16
  const int8_t* pa = Aq + (size_t)(rb * 256 + w64) * 64 + hi * 512 + l31 * 16;
  const int8_t* pb = Wq + (size_t)col0 * 64 + hi * 512 + l31 * 16;

  if (sec < 2) {  // q/k: D = W * X^T
#pragma unroll
    for (int kt = 0; kt < 12; kt++) {
      const int8_t* pak = pa + (size_t)kt * KTA;
      const int8_t* pbk = pb + (size_t)kt * KTB;
      v4i A0a = *(const v4i*)(pak);
      v4i A0b = *(const v4i*)(pak + 1024);
      v4i A1a = *(const v4i*)(pak + 2048);
      v4i A1b = *(const v4i*)(pak + 3072);
      v4i B0a = *(const v4i*)(pbk);
      v4i B0b = *(const v4i*)(pbk + 1024);
      v4i B1a = *(const v4i*)(pbk + 2048);
      v4i B1b = *(const v4i*)(pbk + 3072);
      acc00 = __builtin_amdgcn_mfma_i32_32x32x32_i8(B0a, A0a, acc00, 0, 0, 0);
      acc01 = __builtin_amdgcn_mfma_i32_32x32x32_i8(B1a, A0a, acc01, 0, 0, 0);
      acc10 = __builtin_amdgcn_mfma_i32_32x32x32_i8(B0a, A1a, acc10, 0, 0, 0);
      acc11 = __builtin_amdgcn_mfma_i32_32x32x32_i8(B1a, A1a, acc11, 0, 0, 0);
      acc00 = __builtin_amdgcn_mfma_i32_32x32x32_i8(B0b, A0b, acc00, 0, 0, 0);
      acc01 = __builtin_amdgcn_mfma_i32_32x32x32_i8(B1b, A0b, acc01, 0, 0, 0);
      acc10 = __builtin_amdgcn_mfma_i32_32x32x32_i8(B0b, A1b, acc10, 0, 0, 0);
      acc11 = __builtin_amdgcn_mfma_i32_32x32x32_i8(B1b, A1b, acc11, 0, 0, 0);
    }

    const float* ap = qparams + (sec == 0 ? 0 : 128);
    int8_t* dst = (sec == 0) ? q2 : k2;
    // ---- LN epilogue x2 passes (lane: seq=l31 in group, ch=32i+8b+4hi+c) ---
#pragma unroll
    for (int p = 0; p < 2; p++) {
      float xs[2][16];
#pragma unroll
      for (int i = 0; i < 2; i++)
#pragma unroll
        for (int b = 0; b < 4; b++) {
          int cg = col0 + 32 * i + 8 * b + 4 * hi;
          float4 bqv = *(const float4*)(biasq + cg);
          float4 alv = *(const float4*)(qkv_alpha + cg);
          const float* bqp = (const float*)&bqv;
          const float* alp = (const float*)&alv;
#pragma unroll
          for (int c = 0; c < 4; c++) {
            int av;
            if (p == 0)
              av = (i == 0) ? acc00[4 * b + c] : acc01[4 * b + c];
            else
              av = (i == 0) ? acc10[4 * b + c] : acc11[4 * b + c];
            xs[i][4 * b + c] = fmul(fadd((float)av, bqp[c]), alp[c]);
          }
        }
      // numpy-order stats: acc idx = ch&7 = 4hi+c (lane-local), t = ch>>3
      float rc[4];
#pragma unroll
      for (int c = 0; c < 4; c++) rc[c] = xs[0][c];
#pragma unroll
      for (int b = 1; b < 4; b++)
#pragma unroll
        for (int c = 0; c < 4; c++) rc[c] = fadd(rc[c], xs[0][4 * b + c]);
#pragma unroll
      for (int b = 0; b < 4; b++)
#pragma unroll
        for (int c = 0; c < 4; c++) rc[c] = fadd(rc[c], xs[1][4 * b + c]);
      float Ls = fadd(fadd(rc[0], rc[1]), fadd(rc[2], rc[3]));
      float Rs = __shfl_xor(Ls, 32, 64);
      float mn = fdiv(fadd(Ls, Rs), 64.0f);  // fadd commutative: lanes agree
      float vc[4];
#pragma unroll
      for (int c = 0; c < 4; c++) {
        float d = fsub(xs[0][c], mn);
        vc[c] = fmul(d, d);
      }
#pragma unroll
      for (int b = 1; b < 4; b++)
#pragma unroll
        for (int c = 0; c < 4; c++) {
          float d = fsub(xs[0][4 * b + c], mn);
          vc[c] = fadd(vc[c], fmul(d, d));
        }
#pragma unroll
      for (int b = 0; b < 4; b++)
#pragma unroll
        for (int c = 0; c < 4; c++) {
          float d = fsub(xs[1][4 * b + c], mn);
          vc[c] = fadd(vc[c], fmul(d, d));
        }
      float Lv = fadd(fadd(vc[0], vc[1]), fadd(vc[2], vc[3]));
      float Rv = __shfl_xor(Lv, 32, 64);
      float var = fdiv(fadd(Lv, Rv), 63.0f);
      float den = fadd(__fsqrt_rn(var), 1e-5f);
#pragma unroll
      for (int i = 0; i < 2; i++)
#pragma unroll
        for (int b = 0; b < 4; b++) {
          int cin = 32 * i + 8 * b + 4 * hi;  // channel-in-head
          float4 a4 = *(const float4*)(ap + cin);
          float4 b4 = *(const float4*)(ap + 64 + cin);
          const float* a4p = (const float*)&a4;
          const float* b4p = (const float*)&b4;
          uint32_t pk = 0;
#pragma unroll
          for (int c = 0; c < 4; c++) {
            float xn = fdiv(fsub(xs[i][4 * b + c], mn), den);
            float t = fdiv(fadd(xn, b4p[c]), a4p[c]);
            t = fminf(fmaxf(t, -4.f), 3.f);
            pk |= ((uint32_t)(uint8_t)(int8_t)rintf(t)) << (8 * c);
          }
          *(uint32_t*)&packT[w][l31 * 80 + cin] = pk;
        }
      asm volatile("s_waitcnt lgkmcnt(0)" ::: "memory");
      size_t rowbase = bh * NN + nbase + w64 + p * 32;
#pragma unroll
      for (int c = 0; c < 2; c++) {
        int id = lane + 64 * c;
        int row = id >> 2, off = (id & 3) * 16;  // 32 rows x 64 B
        int4 ov = *(const int4*)&packT[w][row * 80 + off];
        *(int4*)(dst + (rowbase + row) * 64 + off) = ov;
      }
    }
  } else {  // v: D = X * W^T (lane: ch = 32sj + l31, seq = 8b+4hi+c in group)
#pragma unroll
    for (int kt = 0; kt < 12; kt++) {
      const int8_t* pak = pa + (size_t)kt * KTA;
      const int8_t* pbk = pb + (size_t)kt * KTB;
      v4i A0a = *(const v4i*)(pak);
      v4i A0b = *(const v4i*)(pak + 1024);
      v4i A1a = *(const v4i*)(pak + 2048);
      v4i A1b = *(const v4i*)(pak + 3072);
      v4i B0a = *(const v4i*)(pbk);
      v4i B0b = *(const v4i*)(pbk + 1024);
      v4i B1a = *(const v4i*)(pbk + 2048);
      v4i B1b = *(const v4i*)(pbk + 3072);
      acc00 = __builtin_amdgcn_mfma_i32_32x32x32_i8(A0a, B0a, acc00, 0, 0, 0);
      acc01 = __builtin_amdgcn_mfma_i32_32x32x32_i8(A0a, B1a, acc01, 0, 0, 0);
      acc10 = __builtin_amdgcn_mfma_i32_32x32x32_i8(A1a, B0a, acc10, 0, 0, 0);
      acc11 = __builtin_amdgcn_mfma_i32_32x32x32_i8(A1a, B1a, acc11, 0, 0, 0);
      acc00 = __builtin_amdgcn_mfma_i32_32x32x32_i8(A0b, B0b, acc00, 0, 0, 0);
      acc01 = __builtin_amdgcn_mfma_i32_32x32x32_i8(A0b, B1b, acc01, 0, 0, 0);
      acc10 = __builtin_amdgcn_mfma_i32_32x32x32_i8(A1b, B0b, acc10, 0, 0, 0);
      acc11 = __builtin_amdgcn_mfma_i32_32x32x32_i8(A1b, B1b, acc11, 0, 0, 0);
    }

    const float a_in = scal[0], vact = scal[3];
#pragma unroll
    for (int p = 0; p < 2; p++) {
#pragma unroll
      for (int sj = 0; sj < 2; sj++) {
        int cg = col0 + 32 * sj + l31;
        float bq = biasq[cg];
        float va = fdiv(vact, fmul(a_in, qkv_alpha[cg]));
        int dloc = 32 * sj + l31;
#pragma unroll
        for (int b = 0; b < 4; b++) {
          uint32_t pk = 0;
#pragma unroll
          for (int c = 0; c < 4; c++) {
            int av;
            if (p == 0)
              av = (sj == 0) ? acc00[4 * b + c] : acc01[4 * b + c];
            else
              av = (sj == 0) ? acc10[4 * b + c] : acc11[4 * b + c];
            float vint = fadd((float)av, bq);
            float t = fminf(fmaxf(fdiv(vint, va), -4.f), 3.f);
            pk |= ((uint32_t)(uint8_t)(int8_t)rintf(t)) << (8 * c);
          }
          *(uint32_t*)&packT[w][dloc * 48 + 8 * b + 4 * hi] = pk;
        }
      }
      asm volatile("s_waitcnt lgkmcnt(0)" ::: "memory");
      // fragment-major V store: chunk (d=row, n0..n0+15) -> v2f addr
#pragma unroll
      for (int c = 0; c < 2; c++) {
        int id = lane + 64 * c;
        int row = id >> 1, off = (id & 1) * 16;  // 64 d-rows x 32 B
        int4 ov = *(const int4*)&packT[w][row * 48 + off];
        int n0 = nbase + w64 + p * 32 + off;
        *(int4*)(v2f + (size_t)bh * 32768 + ((n0 >> 6) * 4096) +
                 ((row >> 4) * 1024) + ((row & 15) * 64) +
                 (((n0 >> 4) & 3) * 16)) = ov;
      }
    }
  }
}

// ---------------------------------------------------------------------------
// Attention (i8 MFMA), per (qtile64, b*h).  XCD-affine decode: the 8 qt-blocks
// of one (b,h) head run consecutively on one XCD -> K/V head L2-resident.
// Barrier-free K-loops (R13): fragments loaded directly from global (coalesced
// 1KB wave-loads).  R16 register diet: mpack[4..7] lives in LDS (per-wave
// contiguous 1KB slabs -> conflict-free b128), kfr rotation 2-slot.
// Unchanged from R16.
// ---------------------------------------------------------------------------
__global__ __launch_bounds__(256) void attn_kernel(
    const int8_t* __restrict__ q2, const int8_t* __restrict__ k2,
    const int8_t* __restrict__ v2f, const float* __restrict__ scal,
    int8_t* __restrict__ x1q) {
  __shared__ __align__(16) int8_t At[64][80];
  __shared__ __align__(16) uint32_t mpL[4096];  // mpack kt=4..7: 16KB

  const int L = blockIdx.x;
  const int xcd = L & 7, s = L >> 3;
  const int bh = xcd + 8 * (s >> 3);   // head 0..383 (XCD-resident K/V)
  const int qt = s & 7;                // q tile 0..7
  const int tid = threadIdx.x;
  const int w = tid >> 6, lane = tid & 63, quad = lane >> 4, c16 = lane & 15;
  const int sr = tid >> 2, scol = (tid & 3) << 4;
  const float attnm = scal[4];
  const float coef =
      fmul(1.4426950408889634f, fmul(fmul(0.125f, scal[1]), scal[2]));
  const float coef128 = fmul(coef, 128.f);
  const size_t base = (size_t)bh * NN * HD;  // 32768 per head (q2/k2/v2f)
  const int mpbase = w * 1024 + lane * 4;    // per-thread mpL slot base

  // per-lane fragment base pointers (lane offset = c16*64 + quad*16)
  const int8_t* kptr = k2 + base + (size_t)c16 * 64 + quad * 16;
  const int8_t* vptr = v2f + base + (size_t)c16 * 64 + quad * 16;
  v4i qf = *(const v4i*)(q2 + base + (size_t)(qt * 64 + 16 * w + c16) * 64 +
                         quad * 16);

  // ---- pass A: QK^T, m -> regs (kt<4) / LDS (kt>=4), row sums of 2^m ----
  // kf position p = kt*4+f at kptr + p*1024 ; 2-slot rotation
  uint32_t mpack[4][4];
  float Srow = 0.f;
  v4i kfr[2];
  kfr[0] = *(const v4i*)(kptr);
  kfr[1] = *(const v4i*)(kptr + 1024);
#pragma unroll
  for (int kt = 0; kt < 8; kt++) {
    float psum = 0.f;
    uint32_t mp[4];
#pragma unroll
    for (int f = 0; f < 4; f++) {
      int p = kt * 4 + f;
      v4i kf = kfr[p & 1];
      if (p + 2 < 32) kfr[p & 1] = *(const v4i*)(kptr + (p + 2) * 1024);
      v4i d2 = (v4i){0, 0, 0, 0};
      d2 = __builtin_amdgcn_mfma_i32_16x16x64_i8(kf, qf, d2, 0, 0, 0);
      uint32_t pk = 0;
#pragma unroll
      for (int r = 0; r < 4; r++) {
        float e = truncf(fmul(coef128, (float)d2[r]));
        int mi = (int)rintf(fmul(e, 0.0078125f));
        psum = fadd(psum, ldexpf(1.0f, mi));
        pk |= ((uint32_t)(uint8_t)(int8_t)mi) << (8 * r);
      }
      mp[f] = pk;
    }
    if (kt < 4) {
#pragma unroll
      for (int f = 0; f < 4; f++) mpack[kt][f] = mp[f];
    } else {
      int4 st;
      st.x = (int)mp[0]; st.y = (int)mp[1]; st.z = (int)mp[2]; st.w = (int)mp[3];
      *(int4*)&mpL[mpbase + (kt - 4) * 256] = st;
    }
    psum = fadd(psum, __shfl_xor(psum, 16, 64));
    psum = fadd(psum, __shfl_xor(psum, 32, 64));
    Srow = fadd(Srow, psum);
  }
  const float u = fdiv(fdiv(1.0f, Srow), attnm);

  // ---- pass B: requantize from register/LDS m, AV ----
  // vf(kt,s2) = vptr + kt*4096 + s2*1024 ; 4-slot rotation
  v4i xacc[4];
#pragma unroll
  for (int s2 = 0; s2 < 4; s2++) xacc[s2] = (v4i){0, 0, 0, 0};
  v4i vfr[4];
#pragma unroll
  for (int s2 = 0; s2 < 4; s2++)
    vfr[s2] = *(const v4i*)(vptr + s2 * 1024);

#pragma unroll
  for (int kt = 0; kt < 8; kt++) {
    uint32_t mp[4];
    if (kt < 4) {
#pragma unroll
      for (int f = 0; f < 4; f++) mp[f] = mpack[kt][f];
    } else {
      int4 ld = *(const int4*)&mpL[mpbase + (kt - 4) * 256];
      mp[0] = (uint32_t)ld.x; mp[1] = (uint32_t)ld.y;
      mp[2] = (uint32_t)ld.z; mp[3] = (uint32_t)ld.w;
    }
#pragma unroll
    for (int f = 0; f < 4; f++) {
      uint32_t pk = mp[f];
      uint32_t wpk = 0;
#pragma unroll
      for (int r = 0; r < 4; r++) {
        int mi = (int)(int8_t)(pk >> (8 * r));
        float t = fminf(ldexpf(u, mi), 7.f);
        wpk |= ((uint32_t)(uint8_t)(int8_t)rintf(t)) << (8 * r);
      }
      *(uint32_t*)&At[16 * w + c16][16 * f + 4 * quad] = wpk;
    }
    asm volatile("s_waitcnt lgkmcnt(0)" ::: "memory");
    v4i af = *(const v4i*)&At[16 * w + c16][quad * 16];
#pragma unroll
    for (int s2 = 0; s2 < 4; s2++) {
      v4i vf = vfr[s2];
      if (kt < 7)
        vfr[s2] = *(const v4i*)(vptr + (kt + 1) * 4096 + s2 * 1024);
      xacc[s2] = __builtin_amdgcn_mfma_i32_16x16x64_i8(vf, af, xacc[s2], 0, 0, 0);
    }
  }

  // ---- output requant + transpose (reuse At; single barrier) ----
  const float pa = fdiv(scal[5], fmul(attnm, scal[3]));
#pragma unroll
  for (int s2 = 0; s2 < 4; s2++) {
    uint32_t pack = 0;
#pragma unroll
    for (int r = 0; r < 4; r++) {
      float t = fminf(fmaxf(fdiv((float)xacc[s2][r], pa), -4.f), 3.f);
      pack |= ((uint32_t)(uint8_t)(int8_t)rintf(t)) << (8 * r);
    }
    *(uint32_t*)&At[16 * w + c16][16 * s2 + 4 * quad] = pack;
  }
  __syncthreads();
  int4 ov = *(const int4*)&At[sr][scol];
  *(int4*)(x1q + ((size_t)bh * NN + qt * 64 + sr) * HD + scol) = ov;
}

// ---------------------------------------------------------------------------
// GEMM2 (i8 MFMA 32x32x32): barrier-free, LDS-free.  Block = 256seq x 64ch,
// wave = 64x64 (acc = 4 v16i = 64 AGPRs, 4 chains).  R18: K-loop fully
// unrolled, direct loads, scheduler-chosen pipeline depth.
// Epilogue in two 32-row passes.
// ---------------------------------------------------------------------------
__global__ __launch_bounds__(256) void gemm_proj_kernel(
    const int8_t* __restrict__ x1q, const int8_t* __restrict__ Wq,
    const float* __restrict__ proj_alpha, const float* __restrict__ proj_bias,
    const float* __restrict__ scal, float* __restrict__ out) {
  const int L = blockIdx.x;
  const int xcd = L & 7, s = L >> 3;
  const int rb = xcd + 8 * (s / 12);   // 256-row slice 0..63 (XCD-resident)
  const int g = s % 12;                // column block 0..11
  const int tid = threadIdx.x;
  const int w = tid >> 6, lane = tid & 63;
  const int l31 = lane & 31, hi = lane >> 5;
  const int col0 = g * 64;
  const int b_idx = rb >> 1, nbase = (rb & 1) * 256;
  const int w64 = w * 64;

  v16i acc00 = (v16i)(0), acc01 = (v16i)(0);
  v16i acc10 = (v16i)(0), acc11 = (v16i)(0);

  const int8_t* pa =
      x1q + ((size_t)b_idx * HH * NN + nbase + w64 + l31) * 64 + hi * 16;
  const int8_t* pb = Wq + (size_t)col0 * 64 + hi * 512 + l31 * 16;
  const size_t KTX = (size_t)NN * 64;  // head stride in x1q

#pragma unroll
  for (int kt = 0; kt < 12; kt++) {
    const int8_t* pak = pa + (size_t)kt * KTX;
    const int8_t* pbk = pb + (size_t)kt * KTP;
    v4i A0a = *(const v4i*)(pak);
    v4i A0b = *(const v4i*)(pak + 32);
    v4i A1a = *(const v4i*)(pak + 2048);
    v4i A1b = *(const v4i*)(pak + 2048 + 32);
    v4i B0a = *(const v4i*)(pbk);
    v4i B0b = *(const v4i*)(pbk + 1024);
    v4i B1a = *(const v4i*)(pbk + 2048);
    v4i B1b = *(const v4i*)(pbk + 3072);
    acc00 = __builtin_amdgcn_mfma_i32_32x32x32_i8(B0a, A0a, acc00, 0, 0, 0);
    acc01 = __builtin_amdgcn_mfma_i32_32x32x32_i8(B1a, A0a, acc01, 0, 0, 0);
    acc10 = __builtin_amdgcn_mfma_i32_32x32x32_i8(B0a, A1a, acc10, 0, 0, 0);
    acc11 = __builtin_amdgcn_mfma_i32_32x32x32_i8(B1a, A1a, acc11, 0, 0, 0);
    acc00 = __builtin_amdgcn_mfma_i32_32x32x32_i8(B0b, A0b, acc00, 0, 0, 0);
    acc01 = __builtin_amdgcn_mfma_i32_32x32x32_i8(B1b, A0b, acc01, 0, 0, 0);
    acc10 = __builtin_amdgcn_mfma_i32_32x32x32_i8(B0b, A1b, acc10, 0, 0, 0);
    acc11 = __builtin_amdgcn_mfma_i32_32x32x32_i8(B1b, A1b, acc11, 0, 0, 0);
  }

  const float pact = scal[5];
#pragma unroll
  for (int p = 0; p < 2; p++) {
    const int m = rb * 256 + w64 + p * 32 + l31;
#pragma unroll
    for (int i = 0; i < 2; i++)
#pragma unroll
      for (int b = 0; b < 4; b++) {
        int colb = col0 + 32 * i + 8 * b + 4 * hi;
        float4 al = *(const float4*)(proj_alpha + colb);
        float4 bi = *(const float4*)(proj_bias + colb);
        const float* alp = (const float*)&al;
        const float* bip = (const float*)&bi;
        float4 o;
        float* op = (float*)&o;
#pragma unroll
        for (int c = 0; c < 4; c++) {
          int av;
          if (p == 0)
            av = (i == 0) ? acc00[4 * b + c] : acc01[4 * b + c];
          else
            av = (i == 0) ? acc10[4 * b + c] : acc11[4 * b + c];
          op[c] = fadd(fmul(fmul((float)av, alp[c]), pact), bip[c]);
        }
        *(float4*)(out + (size_t)m * CC + colb) = o;
      }
  }
}

extern "C" void kernel_launch(void* const* d_in, const int* in_sizes, int n_in,
                              void* d_out, int out_size, void* d_ws,
                              size_t ws_size, hipStream_t stream) {
  const float* x0 = (const float*)d_in[0];
  const float* qkv_w = (const float*)d_in[1];
  const float* qkv_alpha = (const float*)d_in[2];
  const float* qkv_bias = (const float*)d_in[3];
  const float* qkv_act_alpha = (const float*)d_in[4];
  const float* proj_w = (const float*)d_in[5];
  const float* proj_alpha = (const float*)d_in[6];
  const float* proj_bias = (const float*)d_in[7];
  const float* proj_act_alpha = (const float*)d_in[8];
  const float* normq_w = (const float*)d_in[9];
  const float* normq_b = (const float*)d_in[10];
  const float* normk_w = (const float*)d_in[11];
  const float* normk_b = (const float*)d_in[12];
  const float* qact_alpha = (const float*)d_in[13];
  const float* kact_alpha = (const float*)d_in[14];
  const float* vact_alpha = (const float*)d_in[15];
  const float* attnact_alpha = (const float*)d_in[16];

  char* ws = (char*)d_ws;
  size_t off = 0;
  auto alloc = [&](size_t bytes) -> char* {
    char* p = ws + off;
    off += (bytes + 255) & ~(size_t)255;
    return p;
  };
  float* scal = (float*)alloc(64 * 4);
  float* qparams = (float*)alloc(256 * 4);
  float* biasq = (float*)alloc(QKV_C * 4);
  int8_t* x0q = (int8_t*)alloc((size_t)M_ROWS * CC);   // frag-major [12][...]
  int8_t* wq = (int8_t*)alloc((size_t)QKV_C * CC);     // frag-major [12][...]
  int8_t* pwq = (int8_t*)alloc((size_t)CC * CC);       // frag-major [12][...]
  int8_t* q2 = (int8_t*)alloc((size_t)BB * HH * NN * HD);
  int8_t* k2 = (int8_t*)alloc((size_t)BB * HH * NN * HD);
  int8_t* v2f = (int8_t*)alloc((size_t)BB * HH * NN * HD);  // fragment-major
  int8_t* x1q = (int8_t*)alloc((size_t)M_ROWS * CC);

  prep_kernel<<<1, 256, 0, stream>>>(qkv_act_alpha, proj_act_alpha, qact_alpha,
                                     kact_alpha, vact_alpha, attnact_alpha,
                                     normq_w, normq_b, normk_w, normk_b,
                                     qkv_bias, qkv_alpha, scal, qparams, biasq);

  int total4 = M_ROWS * CC / 4;
  quant_x0_kernel<<<(total4 + 255) / 256, 256, 0, stream>>>(x0, scal, x0q,
                                                            total4);
  quant_w_kernel<<<(QKV_C * CC + 255) / 256, 256, 0, stream>>>(
      qkv_w, qkv_alpha, wq, QKV_C, QKV_C * CC);
  quant_w_kernel<<<(CC * CC + 255) / 256, 256, 0, stream>>>(
      proj_w, proj_alpha, pwq, CC, CC * CC);

  gemm_qkv_kernel<<<36 * (M_ROWS / 256), 256, 0, stream>>>(
      x0q, wq, biasq, scal, qkv_alpha, qparams, q2, k2, v2f);

  attn_kernel<<<(NN / 64) * (BB * HH), 256, 0, stream>>>(q2, k2, v2f, scal,
                                                         x1q);

  gemm_proj_kernel<<<12 * (M_ROWS / 256), 256, 0, stream>>>(
      x1q, pwq, proj_alpha, proj_bias, scal, (float*)d_out);
}

// Round 9
// 272.734 us; speedup vs baseline: 1.3192x; 1.0724x over previous
//
#include <hip/hip_runtime.h>
#include <stdint.h>

// ---------------------------------------------------------------------------
// Q_Attention: quantized ViT attention block, bit-faithful to the JAX/numpy ref.
// B=32, N=512, C=768, H=12, hd=64.  All GEMMs on i8 MFMA (int32 acc, exact).
// R20 = R19 resubmitted (R19 bench was an infra failure, not a kernel error).
//  (1) quant_x0 + quant_w(qkv) + quant_w(proj) fused into ONE dispatch
//      (block-range branch; identical per-element code/addresses ->
//      bit-identical).  7 -> 5 serial launches (~80us of the 283 was
//      inter-launch gap/tail; removes 2 gap pairs).
//  (2) s_setprio(1) around MFMA clusters in gemm_qkv / gemm_proj / attn:
//      all three are barrier-free independent-wave kernels = the structure
//      where T5 measured +4-7% (m191); no arithmetic change.
// K-loop verdict after R12-R18: five structures bracket a ~68us floor at
// MfmaUtil 17% (concurrency-saturated) -- frozen at R16's JIT-B shape.
// ---------------------------------------------------------------------------

#define BB 32
#define NN 512
#define CC 768
#define HH 12
#define HD 64
#define M_ROWS (BB * NN)     // 16384
#define QKV_C (3 * CC)       // 2304
#define KTA ((size_t)M_ROWS * 64)   // x0q kt-slice stride
#define KTB ((size_t)QKV_C * 64)    // wq  kt-slice stride
#define KTP ((size_t)CC * 64)       // pwq kt-slice stride

typedef int v4i __attribute__((ext_vector_type(4)));
typedef int v16i __attribute__((ext_vector_type(16)));

__device__ __forceinline__ float fadd(float a, float b) { return __fadd_rn(a, b); }
__device__ __forceinline__ float fmul(float a, float b) { return __fmul_rn(a, b); }
__device__ __forceinline__ float fdiv(float a, float b) { return __fdiv_rn(a, b); }
__device__ __forceinline__ float fsub(float a, float b) { return __fsub_rn(a, b); }

// numpy pairwise_sum, n=96 (no remainder): 8 accumulators, then pairwise combine
__device__ float np_sum_96(const float* a) {
  float r[8];
#pragma unroll
  for (int j = 0; j < 8; j++) r[j] = a[j];
  for (int i = 8; i < 96; i += 8)
#pragma unroll
    for (int j = 0; j < 8; j++) r[j] = fadd(r[j], a[i + j]);
  return fadd(fadd(fadd(r[0], r[1]), fadd(r[2], r[3])),
              fadd(fadd(r[4], r[5]), fadd(r[6], r[7])));
}

// numpy pairwise mean of 12: 8-acc combine + 4 sequential remainder adds
__device__ float np_mean_12(const float* a) {
  float r[8];
#pragma unroll
  for (int j = 0; j < 8; j++) r[j] = a[j];
  float res = fadd(fadd(fadd(r[0], r[1]), fadd(r[2], r[3])),
                   fadd(fadd(r[4], r[5]), fadd(r[6], r[7])));
  res = fadd(res, a[8]);
  res = fadd(res, a[9]);
  res = fadd(res, a[10]);
  res = fadd(res, a[11]);
  return fdiv(res, 12.0f);
}

// ---------------------------------------------------------------------------
// prep: scalar means + folded LN quant params + integer qkv bias
// scal: [0]=a_in [1]=qact_m [2]=kact_m [3]=vact_m [4]=attnact_m [5]=pact_m
// qparams: [0:64]=qalpha [64:128]=qbias [128:192]=kalpha [192:256]=kbias
// ---------------------------------------------------------------------------
__global__ void prep_kernel(const float* __restrict__ qkv_act_alpha,
                            const float* __restrict__ proj_act_alpha,
                            const float* __restrict__ qact_alpha,
                            const float* __restrict__ kact_alpha,
                            const float* __restrict__ vact_alpha,
                            const float* __restrict__ attnact_alpha,
                            const float* __restrict__ normq_w,
                            const float* __restrict__ normq_b,
                            const float* __restrict__ normk_w,
                            const float* __restrict__ normk_b,
                            const float* __restrict__ qkv_bias,
                            const float* __restrict__ qkv_alpha,
                            float* __restrict__ scal,
                            float* __restrict__ qparams,
                            float* __restrict__ biasq) {
  __shared__ float s_scal[8];
  __shared__ float chunk[16];
  int tid = threadIdx.x;
  if (tid < 8) chunk[tid] = np_sum_96(qkv_act_alpha + 96 * tid);
  else if (tid < 16) chunk[tid] = np_sum_96(proj_act_alpha + 96 * (tid - 8));
  if (tid == 16) s_scal[1] = np_mean_12(qact_alpha);
  if (tid == 17) s_scal[2] = np_mean_12(kact_alpha);
  if (tid == 18) s_scal[3] = np_mean_12(vact_alpha);
  if (tid == 19) s_scal[4] = np_mean_12(attnact_alpha);
  __syncthreads();
  if (tid == 0) {
    float s0 = fadd(fadd(chunk[0], chunk[1]), fadd(chunk[2], chunk[3]));
    float s1 = fadd(fadd(chunk[4], chunk[5]), fadd(chunk[6], chunk[7]));
    s_scal[0] = fdiv(fadd(s0, s1), 768.0f);
    float p0 = fadd(fadd(chunk[8], chunk[9]), fadd(chunk[10], chunk[11]));
    float p1 = fadd(fadd(chunk[12], chunk[13]), fadd(chunk[14], chunk[15]));
    s_scal[5] = fdiv(fadd(p0, p1), 768.0f);
  }
  __syncthreads();
  if (tid < 6) scal[tid] = s_scal[tid];
  if (tid < 64) {
    qparams[tid]       = fdiv(s_scal[1], normq_w[tid]);    // act_a / nw
    qparams[64 + tid]  = fdiv(normq_b[tid], normq_w[tid]); // nb / nw
    qparams[128 + tid] = fdiv(s_scal[2], normk_w[tid]);
    qparams[192 + tid] = fdiv(normk_b[tid], normk_w[tid]);
  }
  float a_in = s_scal[0];
  for (int c = tid; c < QKV_C; c += blockDim.x)
    biasq[c] = truncf(fdiv(fdiv(qkv_bias[c], a_in), qkv_alpha[c]));
}

// fragment-major address within a kt-slice: 32-row groups of 2KB;
// byte (row, b) -> (row&~31)*64 + (b>>4)*512 + (row&31)*16 + (b&15)
__device__ __forceinline__ size_t fragaddr(int row, int b) {
  return (size_t)(row & ~31) * 64 + ((b >> 4) * 512 + (row & 31) * 16 + (b & 15));
}

// ---------------------------------------------------------------------------
// R19 fused quant: blocks [0,12288) = x0 quant; [12288,19200) = qkv_w quant;
// [19200,21504) = proj_w quant.  All counts divide 256 exactly (no bounds
// checks).  Per-element code identical to the three R16 kernels.
// ---------------------------------------------------------------------------
__global__ void quant_all_kernel(const float* __restrict__ x0,
                                 const float* __restrict__ qkv_w,
                                 const float* __restrict__ qkv_alpha,
                                 const float* __restrict__ proj_w,
                                 const float* __restrict__ proj_alpha,
                                 const float* __restrict__ scal,
                                 int8_t* __restrict__ x0q,
                                 int8_t* __restrict__ wq,
                                 int8_t* __restrict__ pwq) {
  const int blk = blockIdx.x;
  if (blk < 12288) {  // x0_q: total4 = 3145728 float4 items
    int i = blk * 256 + threadIdx.x;
    float a_in = scal[0];
    float4 v = ((const float4*)x0)[i];
    char4 o;
    o.x = (int8_t)rintf(fminf(fmaxf(fdiv(v.x, a_in), -8.f), 7.f));
    o.y = (int8_t)rintf(fminf(fmaxf(fdiv(v.y, a_in), -8.f), 7.f));
    o.z = (int8_t)rintf(fminf(fmaxf(fdiv(v.z, a_in), -8.f), 7.f));
    o.w = (int8_t)rintf(fminf(fmaxf(fdiv(v.w, a_in), -8.f), 7.f));
    int seq = i / 192;
    int kp = (i - seq * 192) * 4;  // global channel, multiple of 4
    int b = kp & 63;
    *(char4*)(x0q + (size_t)(kp >> 6) * KTA + fragaddr(seq, b)) = o;
  } else if (blk < 19200) {  // qkv_w: 1769472 elements
    int i = (blk - 12288) * 256 + threadIdx.x;
    int row = i / CC;
    int k = i - row * CC;
    float t = fminf(fmaxf(fdiv(qkv_w[i], qkv_alpha[row]), -8.f), 7.f);
    wq[(size_t)(k >> 6) * ((size_t)QKV_C * 64) + fragaddr(row, k)] =
        (int8_t)rintf(t);
  } else {  // proj_w: 589824 elements
    int i = (blk - 19200) * 256 + threadIdx.x;
    int row = i / CC;
    int k = i - row * CC;
    float t = fminf(fmaxf(fdiv(proj_w[i], proj_alpha[row]), -8.f), 7.f);
    pwq[(size_t)(k >> 6) * ((size_t)CC * 64) + fragaddr(row, k)] =
        (int8_t)rintf(t);
  }
}

// ---------------------------------------------------------------------------
// GEMM1 (i8 MFMA 32x32x32): barrier-free.  Block = 256seq x 64ch; 4 waves
// each own 64seq x 64ch (acc = 4 v16i = 64 AGPRs, 4 independent MFMA chains).
// R16 shape: B loaded just-in-time (L2-hot, 36 sharers); A 1-deep register
// double-buffer.  R19: s_setprio(1) around the 8-MFMA cluster (barrier-free
// independent waves = T5's measured-positive structure).
// Epilogues: two 32-row passes through packT (LDS in-order per wave).
// ---------------------------------------------------------------------------
__global__ __launch_bounds__(256) void gemm_qkv_kernel(
    const int8_t* __restrict__ Aq, const int8_t* __restrict__ Wq,
    const float* __restrict__ biasq, const float* __restrict__ scal,
    const float* __restrict__ qkv_alpha, const float* __restrict__ qparams,
    int8_t* __restrict__ q2, int8_t* __restrict__ k2,
    int8_t* __restrict__ v2f) {
  __shared__ __align__(16) int8_t packT[4][3072];  // per-wave pack tile

  const int L = blockIdx.x;
  const int xcd = L & 7, s = L >> 3;
  const int rb = xcd + 8 * (s / 36);   // A 256-row slice 0..63 (XCD-resident)
  const int g = s % 36;                // column head 0..35
  const int tid = threadIdx.x;
  const int w = tid >> 6, lane = tid & 63;
  const int l31 = lane & 31, hi = lane >> 5;
  const int sec = g / HH, head = g % HH;
  const int col0 = g * 64;
  const int b_idx = rb >> 1, nbase = (rb & 1) * 256;
  const int w64 = w * 64;
  const size_t bh = (size_t)b_idx * HH + head;

  v16i acc00 = (v16i)(0), acc01 = (v16i)(0);
  v16i acc10 = (v16i)(0), acc11 = (v16i)(0);

  // fragment-major pointers: lane offset = hi*512 + l31*16
  const int8_t* pa = Aq + (size_t)(rb * 256 + w64) * 64 + hi * 512 + l31 * 16;
  const int8_t* pb = Wq + (size_t)col0 * 64 + hi * 512 + l31 * 16;

  if (sec < 2) {  // q/k: D = W * X^T
    v4i A0a = *(const v4i*)(pa);
    v4i A0b = *(const v4i*)(pa + 1024);
    v4i A1a = *(const v4i*)(pa + 2048);
    v4i A1b = *(const v4i*)(pa + 3072);
#pragma unroll 1
    for (int kt = 0; kt < 11; kt++) {
      const int8_t* pbk = pb + (size_t)kt * KTB;
      v4i B0a = *(const v4i*)(pbk);
      v4i B0b = *(const v4i*)(pbk + 1024);
      v4i B1a = *(const v4i*)(pbk + 2048);
      v4i B1b = *(const v4i*)(pbk + 3072);
      const int8_t* npa = pa + (size_t)(kt + 1) * KTA;
      v4i nA0a = *(const v4i*)(npa);
      v4i nA0b = *(const v4i*)(npa + 1024);
      v4i nA1a = *(const v4i*)(npa + 2048);
      v4i nA1b = *(const v4i*)(npa + 3072);
      __builtin_amdgcn_s_setprio(1);
      acc00 = __builtin_amdgcn_mfma_i32_32x32x32_i8(B0a, A0a, acc00, 0, 0, 0);
      acc01 = __builtin_amdgcn_mfma_i32_32x32x32_i8(B1a, A0a, acc01, 0, 0, 0);
      acc10 = __builtin_amdgcn_mfma_i32_32x32x32_i8(B0a, A1a, acc10, 0, 0, 0);
      acc11 = __builtin_amdgcn_mfma_i32_32x32x32_i8(B1a, A1a, acc11, 0, 0, 0);
      acc00 = __builtin_amdgcn_mfma_i32_32x32x32_i8(B0b, A0b, acc00, 0, 0, 0);
      acc01 = __builtin_amdgcn_mfma_i32_32x32x32_i8(B1b, A0b, acc01, 0, 0, 0);
      acc10 = __builtin_amdgcn_mfma_i32_32x32x32_i8(B0b, A1b, acc10, 0, 0, 0);
      acc11 = __builtin_amdgcn_mfma_i32_32x32x32_i8(B1b, A1b, acc11, 0, 0, 0);
      __builtin_amdgcn_s_setprio(0);
      A0a = nA0a; A0b = nA0b; A1a = nA1a; A1b = nA1b;
    }
    {  // kt = 11 tail
      const int8_t* pbk = pb + (size_t)11 * KTB;
      v4i B0a = *(const v4i*)(pbk);
      v4i B0b = *(const v4i*)(pbk + 1024);
      v4i B1a = *(const v4i*)(pbk + 2048);
      v4i B1b = *(const v4i*)(pbk + 3072);
      __builtin_amdgcn_s_setprio(1);
      acc00 = __builtin_amdgcn_mfma_i32_32x32x32_i8(B0a, A0a, acc00, 0, 0, 0);
      acc01 = __builtin_amdgcn_mfma_i32_32x32x32_i8(B1a, A0a, acc01, 0, 0, 0);
      acc10 = __builtin_amdgcn_mfma_i32_32x32x32_i8(B0a, A1a, acc10, 0, 0, 0);
      acc11 = __builtin_amdgcn_mfma_i32_32x32x32_i8(B1a, A1a, acc11, 0, 0, 0);
      acc00 = __builtin_amdgcn_mfma_i32_32x32x32_i8(B0b, A0b, acc00, 0, 0, 0);
      acc01 = __builtin_amdgcn_mfma_i32_32x32x32_i8(B1b, A0b, acc01, 0, 0, 0);
      acc10 = __builtin_amdgcn_mfma_i32_32x32x32_i8(B0b, A1b, acc10, 0, 0, 0);
      acc11 = __builtin_amdgcn_mfma_i32_32x32x32_i8(B1b, A1b, acc11, 0, 0, 0);
      __builtin_amdgcn_s_setprio(0);
    }

    const float* ap = qparams + (sec == 0 ? 0 : 128);
    int8_t* dst = (sec == 0) ? q2 : k2;
    // ---- LN epilogue x2 passes (lane: seq=l31 in group, ch=32i+8b+4hi+c) ---
#pragma unroll
    for (int p = 0; p < 2; p++) {
      float xs[2][16];
#pragma unroll
      for (int i = 0; i < 2; i++)
#pragma unroll
        for (int b = 0; b < 4; b++) {
          int cg = col0 + 32 * i + 8 * b + 4 * hi;
          float4 bqv = *(const float4*)(biasq + cg);
          float4 alv = *(const float4*)(qkv_alpha + cg);
          const float* bqp = (const float*)&bqv;
          const float* alp = (const float*)&alv;
#pragma unroll
          for (int c = 0; c < 4; c++) {
            int av;
            if (p == 0)
              av = (i == 0) ? acc00[4 * b + c] : acc01[4 * b + c];
            else
              av = (i == 0) ? acc10[4 * b + c] : acc11[4 * b + c];
            xs[i][4 * b + c] = fmul(fadd((float)av, bqp[c]), alp[c]);
          }
        }
      // numpy-order stats: acc idx = ch&7 = 4hi+c (lane-local), t = ch>>3
      float rc[4];
#pragma unroll
      for (int c = 0; c < 4; c++) rc[c] = xs[0][c];
#pragma unroll
      for (int b = 1; b < 4; b++)
#pragma unroll
        for (int c = 0; c < 4; c++) rc[c] = fadd(rc[c], xs[0][4 * b + c]);
#pragma unroll
      for (int b = 0; b < 4; b++)
#pragma unroll
        for (int c = 0; c < 4; c++) rc[c] = fadd(rc[c], xs[1][4 * b + c]);
      float Ls = fadd(fadd(rc[0], rc[1]), fadd(rc[2], rc[3]));
      float Rs = __shfl_xor(Ls, 32, 64);
      float mn = fdiv(fadd(Ls, Rs), 64.0f);  // fadd commutative: lanes agree
      float vc[4];
#pragma unroll
      for (int c = 0; c < 4; c++) {
        float d = fsub(xs[0][c], mn);
        vc[c] = fmul(d, d);
      }
#pragma unroll
      for (int b = 1; b < 4; b++)
#pragma unroll
        for (int c = 0; c < 4; c++) {
          float d = fsub(xs[0][4 * b + c], mn);
          vc[c] = fadd(vc[c], fmul(d, d));
        }
#pragma unroll
      for (int b = 0; b < 4; b++)
#pragma unroll
        for (int c = 0; c < 4; c++) {
          float d = fsub(xs[1][4 * b + c], mn);
          vc[c] = fadd(vc[c], fmul(d, d));
        }
      float Lv = fadd(fadd(vc[0], vc[1]), fadd(vc[2], vc[3]));
      float Rv = __shfl_xor(Lv, 32, 64);
      float var = fdiv(fadd(Lv, Rv), 63.0f);
      float den = fadd(__fsqrt_rn(var), 1e-5f);
#pragma unroll
      for (int i = 0; i < 2; i++)
#pragma unroll
        for (int b = 0; b < 4; b++) {
          int cin = 32 * i + 8 * b + 4 * hi;  // channel-in-head
          float4 a4 = *(const float4*)(ap + cin);
          float4 b4 = *(const float4*)(ap + 64 + cin);
          const float* a4p = (const float*)&a4;
          const float* b4p = (const float*)&b4;
          uint32_t pk = 0;
#pragma unroll
          for (int c = 0; c < 4; c++) {
            float xn = fdiv(fsub(xs[i][4 * b + c], mn), den);
            float t = fdiv(fadd(xn, b4p[c]), a4p[c]);
            t = fminf(fmaxf(t, -4.f), 3.f);
            pk |= ((uint32_t)(uint8_t)(int8_t)rintf(t)) << (8 * c);
          }
          *(uint32_t*)&packT[w][l31 * 80 + cin] = pk;
        }
      asm volatile("s_waitcnt lgkmcnt(0)" ::: "memory");
      size_t rowbase = bh * NN + nbase + w64 + p * 32;
#pragma unroll
      for (int c = 0; c < 2; c++) {
        int id = lane + 64 * c;
        int row = id >> 2, off = (id & 3) * 16;  // 32 rows x 64 B
        int4 ov = *(const int4*)&packT[w][row * 80 + off];
        *(int4*)(dst + (rowbase + row) * 64 + off) = ov;
      }
    }
  } else {  // v: D = X * W^T (lane: ch = 32sj + l31, seq = 8b+4hi+c in group)
    v4i A0a = *(const v4i*)(pa);
    v4i A0b = *(const v4i*)(pa + 1024);
    v4i A1a = *(const v4i*)(pa + 2048);
    v4i A1b = *(const v4i*)(pa + 3072);
#pragma unroll 1
    for (int kt = 0; kt < 11; kt++) {
      const int8_t* pbk = pb + (size_t)kt * KTB;
      v4i B0a = *(const v4i*)(pbk);
      v4i B0b = *(const v4i*)(pbk + 1024);
      v4i B1a = *(const v4i*)(pbk + 2048);
      v4i B1b = *(const v4i*)(pbk + 3072);
      const int8_t* npa = pa + (size_t)(kt + 1) * KTA;
      v4i nA0a = *(const v4i*)(npa);
      v4i nA0b = *(const v4i*)(npa + 1024);
      v4i nA1a = *(const v4i*)(npa + 2048);
      v4i nA1b = *(const v4i*)(npa + 3072);
      __builtin_amdgcn_s_setprio(1);
      acc00 = __builtin_amdgcn_mfma_i32_32x32x32_i8(A0a, B0a, acc00, 0, 0, 0);
      acc01 = __builtin_amdgcn_mfma_i32_32x32x32_i8(A0a, B1a, acc01, 0, 0, 0);
      acc10 = __builtin_amdgcn_mfma_i32_32x32x32_i8(A1a, B0a, acc10, 0, 0, 0);
      acc11 = __builtin_amdgcn_mfma_i32_32x32x32_i8(A1a, B1a, acc11, 0, 0, 0);
      acc00 = __builtin_amdgcn_mfma_i32_32x32x32_i8(A0b, B0b, acc00, 0, 0, 0);
      acc01 = __builtin_amdgcn_mfma_i32_32x32x32_i8(A0b, B1b, acc01, 0, 0, 0);
      acc10 = __builtin_amdgcn_mfma_i32_32x32x32_i8(A1b, B0b, acc10, 0, 0, 0);
      acc11 = __builtin_amdgcn_mfma_i32_32x32x32_i8(A1b, B1b, acc11, 0, 0, 0);
      __builtin_amdgcn_s_setprio(0);
      A0a = nA0a; A0b = nA0b; A1a = nA1a; A1b = nA1b;
    }
    {  // kt = 11 tail
      const int8_t* pbk = pb + (size_t)11 * KTB;
      v4i B0a = *(const v4i*)(pbk);
      v4i B0b = *(const v4i*)(pbk + 1024);
      v4i B1a = *(const v4i*)(pbk + 2048);
      v4i B1b = *(const v4i*)(pbk + 3072);
      __builtin_amdgcn_s_setprio(1);
      acc00 = __builtin_amdgcn_mfma_i32_32x32x32_i8(A0a, B0a, acc00, 0, 0, 0);
      acc01 = __builtin_amdgcn_mfma_i32_32x32x32_i8(A0a, B1a, acc01, 0, 0, 0);
      acc10 = __builtin_amdgcn_mfma_i32_32x32x32_i8(A1a, B0a, acc10, 0, 0, 0);
      acc11 = __builtin_amdgcn_mfma_i32_32x32x32_i8(A1a, B1a, acc11, 0, 0, 0);
      acc00 = __builtin_amdgcn_mfma_i32_32x32x32_i8(A0b, B0b, acc00, 0, 0, 0);
      acc01 = __builtin_amdgcn_mfma_i32_32x32x32_i8(A0b, B1b, acc01, 0, 0, 0);
      acc10 = __builtin_amdgcn_mfma_i32_32x32x32_i8(A1b, B0b, acc10, 0, 0, 0);
      acc11 = __builtin_amdgcn_mfma_i32_32x32x32_i8(A1b, B1b, acc11, 0, 0, 0);
      __builtin_amdgcn_s_setprio(0);
    }

    const float a_in = scal[0], vact = scal[3];
#pragma unroll
    for (int p = 0; p < 2; p++) {
#pragma unroll
      for (int sj = 0; sj < 2; sj++) {
        int cg = col0 + 32 * sj + l31;
        float bq = biasq[cg];
        float va = fdiv(vact, fmul(a_in, qkv_alpha[cg]));
        int dloc = 32 * sj + l31;
#pragma unroll
        for (int b = 0; b < 4; b++) {
          uint32_t pk = 0;
#pragma unroll
          for (int c = 0; c < 4; c++) {
            int av;
            if (p == 0)
              av = (sj == 0) ? acc00[4 * b + c] : acc01[4 * b + c];
            else
              av = (sj == 0) ? acc10[4 * b + c] : acc11[4 * b + c];
            float vint = fadd((float)av, bq);
            float t = fminf(fmaxf(fdiv(vint, va), -4.f), 3.f);
            pk |= ((uint32_t)(uint8_t)(int8_t)rintf(t)) << (8 * c);
          }
          *(uint32_t*)&packT[w][dloc * 48 + 8 * b + 4 * hi] = pk;
        }
      }
      asm volatile("s_waitcnt lgkmcnt(0)" ::: "memory");
      // fragment-major V store: chunk (d=row, n0..n0+15) -> v2f addr
#pragma unroll
      for (int c = 0; c < 2; c++) {
        int id = lane + 64 * c;
        int row = id >> 1, off = (id & 1) * 16;  // 64 d-rows x 32 B
        int4 ov = *(const int4*)&packT[w][row * 48 + off];
        int n0 = nbase + w64 + p * 32 + off;
        *(int4*)(v2f + (size_t)bh * 32768 + ((n0 >> 6) * 4096) +
                 ((row >> 4) * 1024) + ((row & 15) * 64) +
                 (((n0 >> 4) & 3) * 16)) = ov;
      }
    }
  }
}

// ---------------------------------------------------------------------------
// Attention (i8 MFMA), per (qtile64, b*h).  XCD-affine decode: the 8 qt-blocks
// of one (b,h) head run consecutively on one XCD -> K/V head L2-resident.
// Barrier-free K-loops (R13): fragments loaded directly from global (coalesced
// 1KB wave-loads).  R16 register diet: mpack[4..7] in LDS, kfr 2-slot.
// R19: s_setprio around MFMA (T5: measured +4-7% on attn, m191).
// ---------------------------------------------------------------------------
__global__ __launch_bounds__(256) void attn_kernel(
    const int8_t* __restrict__ q2, const int8_t* __restrict__ k2,
    const int8_t* __restrict__ v2f, const float* __restrict__ scal,
    int8_t* __restrict__ x1q) {
  __shared__ __align__(16) int8_t At[64][80];
  __shared__ __align__(16) uint32_t mpL[4096];  // mpack kt=4..7: 16KB

  const int L = blockIdx.x;
  const int xcd = L & 7, s = L >> 3;
  const int bh = xcd + 8 * (s >> 3);   // head 0..383 (XCD-resident K/V)
  const int qt = s & 7;                // q tile 0..7
  const int tid = threadIdx.x;
  const int w = tid >> 6, lane = tid & 63, quad = lane >> 4, c16 = lane & 15;
  const int sr = tid >> 2, scol = (tid & 3) << 4;
  const float attnm = scal[4];
  const float coef =
      fmul(1.4426950408889634f, fmul(fmul(0.125f, scal[1]), scal[2]));
  const float coef128 = fmul(coef, 128.f);
  const size_t base = (size_t)bh * NN * HD;  // 32768 per head (q2/k2/v2f)
  const int mpbase = w * 1024 + lane * 4;    // per-thread mpL slot base

  // per-lane fragment base pointers (lane offset = c16*64 + quad*16)
  const int8_t* kptr = k2 + base + (size_t)c16 * 64 + quad * 16;
  const int8_t* vptr = v2f + base + (size_t)c16 * 64 + quad * 16;
  v4i qf = *(const v4i*)(q2 + base + (size_t)(qt * 64 + 16 * w + c16) * 64 +
                         quad * 16);

  // ---- pass A: QK^T, m -> regs (kt<4) / LDS (kt>=4), row sums of 2^m ----
  // kf position p = kt*4+f at kptr + p*1024 ; 2-slot rotation
  uint32_t mpack[4][4];
  float Srow = 0.f;
  v4i kfr[2];
  kfr[0] = *(const v4i*)(kptr);
  kfr[1] = *(const v4i*)(kptr + 1024);
#pragma unroll
  for (int kt = 0; kt < 8; kt++) {
    float psum = 0.f;
    uint32_t mp[4];
#pragma unroll
    for (int f = 0; f < 4; f++) {
      int p = kt * 4 + f;
      v4i kf = kfr[p & 1];
      if (p + 2 < 32) kfr[p & 1] = *(const v4i*)(kptr + (p + 2) * 1024);
      v4i d2 = (v4i){0, 0, 0, 0};
      __builtin_amdgcn_s_setprio(1);
      d2 = __builtin_amdgcn_mfma_i32_16x16x64_i8(kf, qf, d2, 0, 0, 0);
      __builtin_amdgcn_s_setprio(0);
      uint32_t pk = 0;
#pragma unroll
      for (int r = 0; r < 4; r++) {
        float e = truncf(fmul(coef128, (float)d2[r]));
        int mi = (int)rintf(fmul(e, 0.0078125f));
        psum = fadd(psum, ldexpf(1.0f, mi));
        pk |= ((uint32_t)(uint8_t)(int8_t)mi) << (8 * r);
      }
      mp[f] = pk;
    }
    if (kt < 4) {
#pragma unroll
      for (int f = 0; f < 4; f++) mpack[kt][f] = mp[f];
    } else {
      int4 st;
      st.x = (int)mp[0]; st.y = (int)mp[1]; st.z = (int)mp[2]; st.w = (int)mp[3];
      *(int4*)&mpL[mpbase + (kt - 4) * 256] = st;
    }
    psum = fadd(psum, __shfl_xor(psum, 16, 64));
    psum = fadd(psum, __shfl_xor(psum, 32, 64));
    Srow = fadd(Srow, psum);
  }
  const float u = fdiv(fdiv(1.0f, Srow), attnm);

  // ---- pass B: requantize from register/LDS m, AV ----
  // vf(kt,s2) = vptr + kt*4096 + s2*1024 ; 4-slot rotation
  v4i xacc[4];
#pragma unroll
  for (int s2 = 0; s2 < 4; s2++) xacc[s2] = (v4i){0, 0, 0, 0};
  v4i vfr[4];
#pragma unroll
  for (int s2 = 0; s2 < 4; s2++)
    vfr[s2] = *(const v4i*)(vptr + s2 * 1024);

#pragma unroll
  for (int kt = 0; kt < 8; kt++) {
    uint32_t mp[4];
    if (kt < 4) {
#pragma unroll
      for (int f = 0; f < 4; f++) mp[f] = mpack[kt][f];
    } else {
      int4 ld = *(const int4*)&mpL[mpbase + (kt - 4) * 256];
      mp[0] = (uint32_t)ld.x; mp[1] = (uint32_t)ld.y;
      mp[2] = (uint32_t)ld.z; mp[3] = (uint32_t)ld.w;
    }
#pragma unroll
    for (int f = 0; f < 4; f++) {
      uint32_t pk = mp[f];
      uint32_t wpk = 0;
#pragma unroll
      for (int r = 0; r < 4; r++) {
        int mi = (int)(int8_t)(pk >> (8 * r));
        float t = fminf(ldexpf(u, mi), 7.f);
        wpk |= ((uint32_t)(uint8_t)(int8_t)rintf(t)) << (8 * r);
      }
      *(uint32_t*)&At[16 * w + c16][16 * f + 4 * quad] = wpk;
    }
    asm volatile("s_waitcnt lgkmcnt(0)" ::: "memory");
    v4i af = *(const v4i*)&At[16 * w + c16][quad * 16];
    __builtin_amdgcn_s_setprio(1);
#pragma unroll
    for (int s2 = 0; s2 < 4; s2++) {
      v4i vf = vfr[s2];
      if (kt < 7)
        vfr[s2] = *(const v4i*)(vptr + (kt + 1) * 4096 + s2 * 1024);
      xacc[s2] = __builtin_amdgcn_mfma_i32_16x16x64_i8(vf, af, xacc[s2], 0, 0, 0);
    }
    __builtin_amdgcn_s_setprio(0);
  }

  // ---- output requant + transpose (reuse At; single barrier) ----
  const float pa = fdiv(scal[5], fmul(attnm, scal[3]));
#pragma unroll
  for (int s2 = 0; s2 < 4; s2++) {
    uint32_t pack = 0;
#pragma unroll
    for (int r = 0; r < 4; r++) {
      float t = fminf(fmaxf(fdiv((float)xacc[s2][r], pa), -4.f), 3.f);
      pack |= ((uint32_t)(uint8_t)(int8_t)rintf(t)) << (8 * r);
    }
    *(uint32_t*)&At[16 * w + c16][16 * s2 + 4 * quad] = pack;
  }
  __syncthreads();
  int4 ov = *(const int4*)&At[sr][scol];
  *(int4*)(x1q + ((size_t)bh * NN + qt * 64 + sr) * HD + scol) = ov;
}

// ---------------------------------------------------------------------------
// GEMM2 (i8 MFMA 32x32x32): barrier-free, LDS-free.  Block = 256seq x 64ch,
// wave = 64x64 (acc = 4 v16i = 64 AGPRs, 4 chains).  B (pwq) loaded
// just-in-time; A (x1q) 1-deep register dbuf.  R19: setprio around MFMA.
// Epilogue in two 32-row passes.
// ---------------------------------------------------------------------------
__global__ __launch_bounds__(256) void gemm_proj_kernel(
    const int8_t* __restrict__ x1q, const int8_t* __restrict__ Wq,
    const float* __restrict__ proj_alpha, const float* __restrict__ proj_bias,
    const float* __restrict__ scal, float* __restrict__ out) {
  const int L = blockIdx.x;
  const int xcd = L & 7, s = L >> 3;
  const int rb = xcd + 8 * (s / 12);   // 256-row slice 0..63 (XCD-resident)
  const int g = s % 12;                // column block 0..11
  const int tid = threadIdx.x;
  const int w = tid >> 6, lane = tid & 63;
  const int l31 = lane & 31, hi = lane >> 5;
  const int col0 = g * 64;
  const int b_idx = rb >> 1, nbase = (rb & 1) * 256;
  const int w64 = w * 64;

  v16i acc00 = (v16i)(0), acc01 = (v16i)(0);
  v16i acc10 = (v16i)(0), acc11 = (v16i)(0);

  const int8_t* pa =
      x1q + ((size_t)b_idx * HH * NN + nbase + w64 + l31) * 64 + hi * 16;
  const int8_t* pb = Wq + (size_t)col0 * 64 + hi * 512 + l31 * 16;
  const size_t KTX = (size_t)NN * 64;  // head stride in x1q

  v4i A0a = *(const v4i*)(pa);
  v4i A0b = *(const v4i*)(pa + 32);
  v4i A1a = *(const v4i*)(pa + 2048);
  v4i A1b = *(const v4i*)(pa + 2048 + 32);
#pragma unroll 1
  for (int kt = 0; kt < 11; kt++) {
    const int8_t* pbk = pb + (size_t)kt * KTP;
    v4i B0a = *(const v4i*)(pbk);
    v4i B0b = *(const v4i*)(pbk + 1024);
    v4i B1a = *(const v4i*)(pbk + 2048);
    v4i B1b = *(const v4i*)(pbk + 3072);
    const int8_t* npa = pa + (size_t)(kt + 1) * KTX;
    v4i nA0a = *(const v4i*)(npa);
    v4i nA0b = *(const v4i*)(npa + 32);
    v4i nA1a = *(const v4i*)(npa + 2048);
    v4i nA1b = *(const v4i*)(npa + 2048 + 32);
    __builtin_amdgcn_s_setprio(1);
    acc00 = __builtin_amdgcn_mfma_i32_32x32x32_i8(B0a, A0a, acc00, 0, 0, 0);
    acc01 = __builtin_amdgcn_mfma_i32_32x32x32_i8(B1a, A0a, acc01, 0, 0, 0);
    acc10 = __builtin_amdgcn_mfma_i32_32x32x32_i8(B0a, A1a, acc10, 0, 0, 0);
    acc11 = __builtin_amdgcn_mfma_i32_32x32x32_i8(B1a, A1a, acc11, 0, 0, 0);
    acc00 = __builtin_amdgcn_mfma_i32_32x32x32_i8(B0b, A0b, acc00, 0, 0, 0);
    acc01 = __builtin_amdgcn_mfma_i32_32x32x32_i8(B1b, A0b, acc01, 0, 0, 0);
    acc10 = __builtin_amdgcn_mfma_i32_32x32x32_i8(B0b, A1b, acc10, 0, 0, 0);
    acc11 = __builtin_amdgcn_mfma_i32_32x32x32_i8(B1b, A1b, acc11, 0, 0, 0);
    __builtin_amdgcn_s_setprio(0);
    A0a = nA0a; A0b = nA0b; A1a = nA1a; A1b = nA1b;
  }
  {  // kt = 11 tail
    const int8_t* pbk = pb + (size_t)11 * KTP;
    v4i B0a = *(const v4i*)(pbk);
    v4i B0b = *(const v4i*)(pbk + 1024);
    v4i B1a = *(const v4i*)(pbk + 2048);
    v4i B1b = *(const v4i*)(pbk + 3072);
    __builtin_amdgcn_s_setprio(1);
    acc00 = __builtin_amdgcn_mfma_i32_32x32x32_i8(B0a, A0a, acc00, 0, 0, 0);
    acc01 = __builtin_amdgcn_mfma_i32_32x32x32_i8(B1a, A0a, acc01, 0, 0, 0);
    acc10 = __builtin_amdgcn_mfma_i32_32x32x32_i8(B0a, A1a, acc10, 0, 0, 0);
    acc11 = __builtin_amdgcn_mfma_i32_32x32x32_i8(B1a, A1a, acc11, 0, 0, 0);
    acc00 = __builtin_amdgcn_mfma_i32_32x32x32_i8(B0b, A0b, acc00, 0, 0, 0);
    acc01 = __builtin_amdgcn_mfma_i32_32x32x32_i8(B1b, A0b, acc01, 0, 0, 0);
    acc10 = __builtin_amdgcn_mfma_i32_32x32x32_i8(B0b, A1b, acc10, 0, 0, 0);
    acc11 = __builtin_amdgcn_mfma_i32_32x32x32_i8(B1b, A1b, acc11, 0, 0, 0);
    __builtin_amdgcn_s_setprio(0);
  }

  const float pact = scal[5];
#pragma unroll
  for (int p = 0; p < 2; p++) {
    const int m = rb * 256 + w64 + p * 32 + l31;
#pragma unroll
    for (int i = 0; i < 2; i++)
#pragma unroll
      for (int b = 0; b < 4; b++) {
        int colb = col0 + 32 * i + 8 * b + 4 * hi;
        float4 al = *(const float4*)(proj_alpha + colb);
        float4 bi = *(const float4*)(proj_bias + colb);
        const float* alp = (const float*)&al;
        const float* bip = (const float*)&bi;
        float4 o;
        float* op = (float*)&o;
#pragma unroll
        for (int c = 0; c < 4; c++) {
          int av;
          if (p == 0)
            av = (i == 0) ? acc00[4 * b + c] : acc01[4 * b + c];
          else
            av = (i == 0) ? acc10[4 * b + c] : acc11[4 * b + c];
          op[c] = fadd(fmul(fmul((float)av, alp[c]), pact), bip[c]);
        }
        *(float4*)(out + (size_t)m * CC + colb) = o;
      }
  }
}

extern "C" void kernel_launch(void* const* d_in, const int* in_sizes, int n_in,
                              void* d_out, int out_size, void* d_ws,
                              size_t ws_size, hipStream_t stream) {
  const float* x0 = (const float*)d_in[0];
  const float* qkv_w = (const float*)d_in[1];
  const float* qkv_alpha = (const float*)d_in[2];
  const float* qkv_bias = (const float*)d_in[3];
  const float* qkv_act_alpha = (const float*)d_in[4];
  const float* proj_w = (const float*)d_in[5];
  const float* proj_alpha = (const float*)d_in[6];
  const float* proj_bias = (const float*)d_in[7];
  const float* proj_act_alpha = (const float*)d_in[8];
  const float* normq_w = (const float*)d_in[9];
  const float* normq_b = (const float*)d_in[10];
  const float* normk_w = (const float*)d_in[11];
  const float* normk_b = (const float*)d_in[12];
  const float* qact_alpha = (const float*)d_in[13];
  const float* kact_alpha = (const float*)d_in[14];
  const float* vact_alpha = (const float*)d_in[15];
  const float* attnact_alpha = (const float*)d_in[16];

  char* ws = (char*)d_ws;
  size_t off = 0;
  auto alloc = [&](size_t bytes) -> char* {
    char* p = ws + off;
    off += (bytes + 255) & ~(size_t)255;
    return p;
  };
  float* scal = (float*)alloc(64 * 4);
  float* qparams = (float*)alloc(256 * 4);
  float* biasq = (float*)alloc(QKV_C * 4);
  int8_t* x0q = (int8_t*)alloc((size_t)M_ROWS * CC);   // frag-major [12][...]
  int8_t* wq = (int8_t*)alloc((size_t)QKV_C * CC);     // frag-major [12][...]
  int8_t* pwq = (int8_t*)alloc((size_t)CC * CC);       // frag-major [12][...]
  int8_t* q2 = (int8_t*)alloc((size_t)BB * HH * NN * HD);
  int8_t* k2 = (int8_t*)alloc((size_t)BB * HH * NN * HD);
  int8_t* v2f = (int8_t*)alloc((size_t)BB * HH * NN * HD);  // fragment-major
  int8_t* x1q = (int8_t*)alloc((size_t)M_ROWS * CC);

  prep_kernel<<<1, 256, 0, stream>>>(qkv_act_alpha, proj_act_alpha, qact_alpha,
                                     kact_alpha, vact_alpha, attnact_alpha,
                                     normq_w, normq_b, normk_w, normk_b,
                                     qkv_bias, qkv_alpha, scal, qparams, biasq);

  // fused quant: 12288 (x0) + 6912 (qkv_w) + 2304 (proj_w) = 21504 blocks
  quant_all_kernel<<<21504, 256, 0, stream>>>(x0, qkv_w, qkv_alpha, proj_w,
                                              proj_alpha, scal, x0q, wq, pwq);

  gemm_qkv_kernel<<<36 * (M_ROWS / 256), 256, 0, stream>>>(
      x0q, wq, biasq, scal, qkv_alpha, qparams, q2, k2, v2f);

  attn_kernel<<<(NN / 64) * (BB * HH), 256, 0, stream>>>(q2, k2, v2f, scal,
                                                         x1q);

  gemm_proj_kernel<<<12 * (M_ROWS / 256), 256, 0, stream>>>(
      x1q, pwq, proj_alpha, proj_bias, scal, (float*)d_out);
}